// Round 2
// baseline (1685.508 us; speedup 1.0000x reference)
//
#include <hip/hip_runtime.h>
#include <hip/hip_bf16.h>
#include <math.h>

#define NN 100000
#define NE 1600000
#define NP 500000
#define HD 128

// ---------------- degree ----------------
__global__ void k_fill1(float* deg, int n) {
  int i = blockIdx.x * 256 + threadIdx.x;
  if (i < n) deg[i] = 1.0f;  // self-loop counts 1
}

__global__ void k_degcount(const int* __restrict__ dst, float* deg, int ne) {
  int e = blockIdx.x * 256 + threadIdx.x;
  if (e < ne) atomicAdd(deg + dst[e], 1.0f);
}

__global__ void k_rsqrt(float* d, int n) {
  int i = blockIdx.x * 256 + threadIdx.x;
  if (i < n) d[i] = rsqrtf(d[i]);
}

// ---------------- GEMM: Y[n,128] = act(X[n,128]) @ W[128,128] ----------------
// Block: 256 threads, 64-row tile staged in LDS; thread = 8 rows x 4 cols.
template <bool RELU>
__global__ __launch_bounds__(256) void k_gemm128(const float* __restrict__ X,
                                                 const float* __restrict__ W,
                                                 float* __restrict__ Y, int nrows) {
  __shared__ float xs[64 * 128];  // 32 KB
  const int tid = threadIdx.x;
  const int row0 = blockIdx.x * 64;
  const int valid = min(64, nrows - row0);

  const float4* Xv = (const float4*)(X + (size_t)row0 * HD);
  float4* xsv = (float4*)xs;
#pragma unroll
  for (int it = 0; it < 8; ++it) {
    int idx = it * 256 + tid;       // float4 idx within tile, 0..2047
    int r = idx >> 5;               // 32 float4 per row
    float4 v = make_float4(0.f, 0.f, 0.f, 0.f);
    if (r < valid) v = Xv[idx];
    if (RELU) {
      v.x = fmaxf(v.x, 0.f); v.y = fmaxf(v.y, 0.f);
      v.z = fmaxf(v.z, 0.f); v.w = fmaxf(v.w, 0.f);
    }
    xsv[idx] = v;
  }
  __syncthreads();

  const int c4 = tid & 31;          // float4 column index (col = c4*4)
  const int rb = (tid >> 5) * 8;    // first of 8 rows
  float acc[8][4];
#pragma unroll
  for (int r = 0; r < 8; ++r)
#pragma unroll
    for (int c = 0; c < 4; ++c) acc[r][c] = 0.f;

  const float4* Wv = (const float4*)W;
  for (int k = 0; k < 128; ++k) {
    float4 w = Wv[k * 32 + c4];
    float xv[8];
#pragma unroll
    for (int r = 0; r < 8; ++r) xv[r] = xs[(rb + r) * HD + k];
#pragma unroll
    for (int r = 0; r < 8; ++r) {
      acc[r][0] += xv[r] * w.x; acc[r][1] += xv[r] * w.y;
      acc[r][2] += xv[r] * w.z; acc[r][3] += xv[r] * w.w;
    }
  }

#pragma unroll
  for (int r = 0; r < 8; ++r) {
    int row = row0 + rb + r;
    if (row < nrows) {
      float4 o = make_float4(acc[r][0], acc[r][1], acc[r][2], acc[r][3]);
      ((float4*)(Y + (size_t)row * HD))[c4] = o;
    }
  }
}

// ---------------- agg init: agg = dinv^2 * h + b ----------------
__global__ void k_self_bias(const float* __restrict__ h, const float* __restrict__ dinv,
                            const float* __restrict__ b, float* __restrict__ agg, int n) {
  int gid = blockIdx.x * 256 + threadIdx.x;  // float4 index over n*32
  if (gid < n * 32) {
    int node = gid >> 5;
    int f4 = gid & 31;
    float di = dinv[node];
    di = di * di;
    float4 hv = ((const float4*)h)[gid];
    float4 bv = ((const float4*)b)[f4];
    float4 o = make_float4(di * hv.x + bv.x, di * hv.y + bv.y,
                           di * hv.z + bv.z, di * hv.w + bv.w);
    ((float4*)agg)[gid] = o;
  }
}

// ---------------- edge scatter: agg[dst] += h[src] * dinv[src]*dinv[dst] ----------------
// Block 256 = 2 edges x 128 features.
__global__ __launch_bounds__(256) void k_scatter(const float* __restrict__ h,
                                                 const float* __restrict__ dinv,
                                                 const int* __restrict__ src,
                                                 const int* __restrict__ dst,
                                                 float* __restrict__ agg, int ne) {
  int e = blockIdx.x * 2 + (threadIdx.x >> 7);
  int f = threadIdx.x & 127;
  if (e < ne) {
    int s = src[e], d = dst[e];
    float nrm = dinv[s] * dinv[d];
    float v = h[(size_t)s * HD + f] * nrm;
    atomicAdd(agg + (size_t)d * HD + f, v);
  }
}

// ---------------- per-node scores: s[2n]=h2[n].Wl[:128], s[2n+1]=h2[n].Wl[128:] ----------------
__global__ __launch_bounds__(256) void k_score(const float* __restrict__ h,
                                               const float* __restrict__ Wl,
                                               float* __restrict__ s, int n) {
  int node = blockIdx.x * 4 + (threadIdx.x >> 6);
  int lane = threadIdx.x & 63;
  if (node >= n) return;
  float h0 = h[(size_t)node * HD + lane];
  float h1 = h[(size_t)node * HD + 64 + lane];
  float p1 = h0 * Wl[lane] + h1 * Wl[64 + lane];
  float p2 = h0 * Wl[128 + lane] + h1 * Wl[192 + lane];
#pragma unroll
  for (int o = 32; o > 0; o >>= 1) {
    p1 += __shfl_down(p1, o);
    p2 += __shfl_down(p2, o);
  }
  if (lane == 0) {
    s[node * 2] = p1;
    s[node * 2 + 1] = p2;
  }
}

// ---------------- pair outputs ----------------
__global__ void k_pairs(const float* __restrict__ s, const int* __restrict__ I,
                        const int* __restrict__ J, const float* __restrict__ blin,
                        float* __restrict__ out, int np) {
  int p = blockIdx.x * 256 + threadIdx.x;
  if (p < np) {
    float v = s[2 * I[p]] + s[2 * J[p] + 1] + blin[0];
    out[p] = 1.f / (1.f + __expf(-v));
  }
}

extern "C" void kernel_launch(void* const* d_in, const int* in_sizes, int n_in,
                              void* d_out, int out_size, void* d_ws, size_t ws_size,
                              hipStream_t stream) {
  const float* x     = (const float*)d_in[0];
  const int*   eidx  = (const int*)d_in[1];
  const int*   Iidx  = (const int*)d_in[2];
  const int*   Jidx  = (const int*)d_in[3];
  const float* W1    = (const float*)d_in[4];
  const float* b1    = (const float*)d_in[5];
  const float* W2    = (const float*)d_in[6];
  const float* b2    = (const float*)d_in[7];
  const float* Wlin  = (const float*)d_in[8];
  const float* blin  = (const float*)d_in[9];
  const int* src = eidx;
  const int* dst = eidx + NE;

  float* ws = (float*)d_ws;
  float* dinv = ws;                       // N floats
  float* hA   = dinv + NN;                // N*128
  float* hB   = hA + (size_t)NN * HD;     // N*128
  float* sv   = hB + (size_t)NN * HD;     // 2N

  float* out = (float*)d_out;

  // degree -> dinv
  k_fill1<<<(NN + 255) / 256, 256, 0, stream>>>(dinv, NN);
  k_degcount<<<(NE + 255) / 256, 256, 0, stream>>>(dst, dinv, NE);
  k_rsqrt<<<(NN + 255) / 256, 256, 0, stream>>>(dinv, NN);

  const int gemm_grid = (NN + 63) / 64;
  const int sb_grid = (NN * 32 + 255) / 256;
  const int sc_grid = (NE + 1) / 2;

  // conv1: hA = x@W1 ; hB = dinv^2*hA + b1 ; hB += scatter(hA)
  k_gemm128<false><<<gemm_grid, 256, 0, stream>>>(x, W1, hA, NN);
  k_self_bias<<<sb_grid, 256, 0, stream>>>(hA, dinv, b1, hB, NN);
  k_scatter<<<sc_grid, 256, 0, stream>>>(hA, dinv, src, dst, hB, NE);

  // conv2: hA = relu(hB)@W2 ; hB' = dinv^2*hA + b2 ; hB' += scatter(hA)
  k_gemm128<true><<<gemm_grid, 256, 0, stream>>>(hB, W2, hA, NN);
  k_self_bias<<<sb_grid, 256, 0, stream>>>(hA, dinv, b2, hB, NN);
  k_scatter<<<sc_grid, 256, 0, stream>>>(hA, dinv, src, dst, hB, NE);

  // scoring
  k_score<<<(NN + 3) / 4, 256, 0, stream>>>(hB, Wlin, sv, NN);
  k_pairs<<<(NP + 255) / 256, 256, 0, stream>>>(sv, Iidx, Jidx, blin, out, NP);
}

// Round 3
// 670.468 us; speedup vs baseline: 2.5139x; 2.5139x over previous
//
#include <hip/hip_runtime.h>
#include <hip/hip_bf16.h>
#include <math.h>

#define NN 100000
#define NE 1600000
#define NP 500000
#define HD 128
#define SCAN_ELEMS 1024
#define NBLK 98           // ceil(NN/1024)
#define NPAD (NBLK * SCAN_ELEMS)  // 100352

// ---------------- CSR build ----------------
__global__ void k_zero_int(int* p, int n) {
  int i = blockIdx.x * 256 + threadIdx.x;
  if (i < n) p[i] = 0;
}

__global__ void k_count(const int* __restrict__ dst, int* __restrict__ cnt, int ne) {
  int e = blockIdx.x * 256 + threadIdx.x;
  if (e < ne) atomicAdd(cnt + dst[e], 1);
}

// dinv[i] = rsqrt(cnt[i] + 1)  (self-loop)
__global__ void k_dinv(const int* __restrict__ cnt, float* __restrict__ dinv, int n) {
  int i = blockIdx.x * 256 + threadIdx.x;
  if (i < n) dinv[i] = rsqrtf((float)cnt[i] + 1.0f);
}

// Per-block exclusive scan of 1024 ints (256 threads x 4), block total -> bsum.
__global__ __launch_bounds__(256) void k_scan1(const int* __restrict__ cnt,
                                               int* __restrict__ rowptr,
                                               int* __restrict__ bsum) {
  __shared__ int sh[256];
  const int t = threadIdx.x;
  const int base = blockIdx.x * SCAN_ELEMS + t * 4;
  int4 v = ((const int4*)cnt)[blockIdx.x * 256 + t];
  int s0 = v.x, s1 = s0 + v.y, s2 = s1 + v.z, s3 = s2 + v.w;
  sh[t] = s3;
  __syncthreads();
  int run = s3;
#pragma unroll
  for (int o = 1; o < 256; o <<= 1) {
    int add = (t >= o) ? sh[t - o] : 0;
    __syncthreads();
    sh[t] += add;
    __syncthreads();
  }
  int exc = sh[t] - run;  // exclusive prefix of this thread's chunk
  if (base + 0 < NN) rowptr[base + 0] = exc;
  if (base + 1 < NN) rowptr[base + 1] = exc + s0;
  if (base + 2 < NN) rowptr[base + 2] = exc + s1;
  if (base + 3 < NN) rowptr[base + 3] = exc + s2;
  if (t == 255) bsum[blockIdx.x] = sh[255];
}

// Exclusive scan of NBLK block sums, single block of 128 threads.
__global__ __launch_bounds__(128) void k_scan2(int* __restrict__ bsum) {
  __shared__ int sh[128];
  const int t = threadIdx.x;
  int v = (t < NBLK) ? bsum[t] : 0;
  sh[t] = v;
  __syncthreads();
#pragma unroll
  for (int o = 1; o < 128; o <<= 1) {
    int add = (t >= o) ? sh[t - o] : 0;
    __syncthreads();
    sh[t] += add;
    __syncthreads();
  }
  if (t < NBLK) bsum[t] = sh[t] - v;
}

// rowptr[i] += bsum[block]; cursor[i] = rowptr[i]; rowptr[NN] = NE.
__global__ __launch_bounds__(256) void k_scan3(int* __restrict__ rowptr,
                                               int* __restrict__ cursor,
                                               const int* __restrict__ bsum) {
  const int t = threadIdx.x;
  const int base = blockIdx.x * SCAN_ELEMS + t * 4;
  const int off = bsum[blockIdx.x];
#pragma unroll
  for (int k = 0; k < 4; ++k) {
    int i = base + k;
    if (i < NN) {
      int r = rowptr[i] + off;
      rowptr[i] = r;
      cursor[i] = r;
    }
  }
  if (blockIdx.x == 0 && t == 0) rowptr[NN] = NE;
}

__global__ void k_fillcsr(const int* __restrict__ src, const int* __restrict__ dst,
                          int* __restrict__ cursor, int* __restrict__ col, int ne) {
  int e = blockIdx.x * 256 + threadIdx.x;
  if (e < ne) {
    int pos = atomicAdd(cursor + dst[e], 1);
    col[pos] = src[e];
  }
}

// ---------------- GEMM: Y[n,128] = dinv[n] * act(X[n,128]) @ W[128,128] ----------------
template <bool RELU>
__global__ __launch_bounds__(256) void k_gemm128(const float* __restrict__ X,
                                                 const float* __restrict__ W,
                                                 const float* __restrict__ dinv,
                                                 float* __restrict__ Y, int nrows) {
  __shared__ float xs[64 * 128];  // 32 KB
  const int tid = threadIdx.x;
  const int row0 = blockIdx.x * 64;
  const int valid = min(64, nrows - row0);

  const float4* Xv = (const float4*)(X + (size_t)row0 * HD);
  float4* xsv = (float4*)xs;
#pragma unroll
  for (int it = 0; it < 8; ++it) {
    int idx = it * 256 + tid;       // float4 idx within tile, 0..2047
    int r = idx >> 5;               // 32 float4 per row
    float4 v = make_float4(0.f, 0.f, 0.f, 0.f);
    if (r < valid) v = Xv[idx];
    if (RELU) {
      v.x = fmaxf(v.x, 0.f); v.y = fmaxf(v.y, 0.f);
      v.z = fmaxf(v.z, 0.f); v.w = fmaxf(v.w, 0.f);
    }
    xsv[idx] = v;
  }
  __syncthreads();

  const int c4 = tid & 31;          // float4 column index
  const int rb = (tid >> 5) * 8;    // first of 8 rows
  float acc[8][4];
#pragma unroll
  for (int r = 0; r < 8; ++r)
#pragma unroll
    for (int c = 0; c < 4; ++c) acc[r][c] = 0.f;

  const float4* Wv = (const float4*)W;
  for (int k = 0; k < 128; ++k) {
    float4 w = Wv[k * 32 + c4];
    float xv[8];
#pragma unroll
    for (int r = 0; r < 8; ++r) xv[r] = xs[(rb + r) * HD + k];
#pragma unroll
    for (int r = 0; r < 8; ++r) {
      acc[r][0] += xv[r] * w.x; acc[r][1] += xv[r] * w.y;
      acc[r][2] += xv[r] * w.z; acc[r][3] += xv[r] * w.w;
    }
  }

#pragma unroll
  for (int r = 0; r < 8; ++r) {
    int row = row0 + rb + r;
    if (row < nrows) {
      float dr = dinv[row];
      float4 o = make_float4(acc[r][0] * dr, acc[r][1] * dr,
                             acc[r][2] * dr, acc[r][3] * dr);
      ((float4*)(Y + (size_t)row * HD))[c4] = o;
    }
  }
}

// ---------------- gather aggregate ----------------
// out[n] = dinv[n] * (sum_{s in inNbrs(n)} hs[s] + hs[n]) + b
// One wave per node; lane covers 2 features (float2).
__global__ __launch_bounds__(256) void k_gather(const float* __restrict__ hs,
                                                const float* __restrict__ dinv,
                                                const int* __restrict__ rowptr,
                                                const int* __restrict__ col,
                                                const float* __restrict__ bias,
                                                float* __restrict__ outp, int n) {
  int node = blockIdx.x * 4 + (threadIdx.x >> 6);
  int lane = threadIdx.x & 63;
  if (node >= n) return;
  int beg = rowptr[node], end = rowptr[node + 1];

  const float2* hv = (const float2*)hs;
  float2 acc = hv[(size_t)node * 64 + lane];  // self term
  int e = beg;
  for (; e + 1 < end; e += 2) {
    int s0 = col[e], s1 = col[e + 1];
    float2 v0 = hv[(size_t)s0 * 64 + lane];
    float2 v1 = hv[(size_t)s1 * 64 + lane];
    acc.x += v0.x + v1.x;
    acc.y += v0.y + v1.y;
  }
  if (e < end) {
    int s0 = col[e];
    float2 v0 = hv[(size_t)s0 * 64 + lane];
    acc.x += v0.x;
    acc.y += v0.y;
  }
  float di = dinv[node];
  float2 b = ((const float2*)bias)[lane];
  float2 o = make_float2(acc.x * di + b.x, acc.y * di + b.y);
  ((float2*)outp)[(size_t)node * 64 + lane] = o;
}

// ---------------- per-node scores ----------------
__global__ __launch_bounds__(256) void k_score(const float* __restrict__ h,
                                               const float* __restrict__ Wl,
                                               float* __restrict__ s, int n) {
  int node = blockIdx.x * 4 + (threadIdx.x >> 6);
  int lane = threadIdx.x & 63;
  if (node >= n) return;
  float h0 = h[(size_t)node * HD + lane];
  float h1 = h[(size_t)node * HD + 64 + lane];
  float p1 = h0 * Wl[lane] + h1 * Wl[64 + lane];
  float p2 = h0 * Wl[128 + lane] + h1 * Wl[192 + lane];
#pragma unroll
  for (int o = 32; o > 0; o >>= 1) {
    p1 += __shfl_down(p1, o);
    p2 += __shfl_down(p2, o);
  }
  if (lane == 0) {
    s[node * 2] = p1;
    s[node * 2 + 1] = p2;
  }
}

// ---------------- pair outputs ----------------
__global__ void k_pairs(const float* __restrict__ s, const int* __restrict__ I,
                        const int* __restrict__ J, const float* __restrict__ blin,
                        float* __restrict__ out, int np) {
  int p = blockIdx.x * 256 + threadIdx.x;
  if (p < np) {
    float v = s[2 * I[p]] + s[2 * J[p] + 1] + blin[0];
    out[p] = 1.f / (1.f + __expf(-v));
  }
}

extern "C" void kernel_launch(void* const* d_in, const int* in_sizes, int n_in,
                              void* d_out, int out_size, void* d_ws, size_t ws_size,
                              hipStream_t stream) {
  const float* x     = (const float*)d_in[0];
  const int*   eidx  = (const int*)d_in[1];
  const int*   Iidx  = (const int*)d_in[2];
  const int*   Jidx  = (const int*)d_in[3];
  const float* W1    = (const float*)d_in[4];
  const float* b1    = (const float*)d_in[5];
  const float* W2    = (const float*)d_in[6];
  const float* b2    = (const float*)d_in[7];
  const float* Wlin  = (const float*)d_in[8];
  const float* blin  = (const float*)d_in[9];
  const int* src = eidx;
  const int* dst = eidx + NE;

  // workspace layout (floats/ints, all 16B aligned)
  float* ws   = (float*)d_ws;
  float* dinv = ws;                           // NN
  float* hA   = dinv + 100000;                // NN*128
  float* hB   = hA + (size_t)NN * HD;         // NN*128
  float* sv   = hB + (size_t)NN * HD;         // 2*NN
  int* cnt    = (int*)(sv + 200000);          // NPAD (100352)
  int* rowptr = cnt + NPAD;                   // NN+1 -> pad 100004
  int* cursor = rowptr + 100004;              // NN
  int* col    = cursor + 100000;              // NE
  int* bsum   = col + NE;                     // NBLK -> pad 128

  float* out = (float*)d_out;

  // ---- CSR build (once, reused by both convs) ----
  k_zero_int<<<(NPAD + 255) / 256, 256, 0, stream>>>(cnt, NPAD);
  k_count<<<(NE + 255) / 256, 256, 0, stream>>>(dst, cnt, NE);
  k_dinv<<<(NN + 255) / 256, 256, 0, stream>>>(cnt, dinv, NN);
  k_scan1<<<NBLK, 256, 0, stream>>>(cnt, rowptr, bsum);
  k_scan2<<<1, 128, 0, stream>>>(bsum);
  k_scan3<<<NBLK, 256, 0, stream>>>(rowptr, cursor, bsum);
  k_fillcsr<<<(NE + 255) / 256, 256, 0, stream>>>(src, dst, cursor, col, NE);

  const int gemm_grid = (NN + 63) / 64;
  const int gth_grid = (NN + 3) / 4;

  // conv1: hA = dinv * (x@W1); hB = dinv*(gather(hA)+hA) + b1
  k_gemm128<false><<<gemm_grid, 256, 0, stream>>>(x, W1, dinv, hA, NN);
  k_gather<<<gth_grid, 256, 0, stream>>>(hA, dinv, rowptr, col, b1, hB, NN);

  // conv2: hA = dinv * (relu(hB)@W2); hB = dinv*(gather(hA)+hA) + b2
  k_gemm128<true><<<gemm_grid, 256, 0, stream>>>(hB, W2, dinv, hA, NN);
  k_gather<<<gth_grid, 256, 0, stream>>>(hA, dinv, rowptr, col, b2, hB, NN);

  // scoring
  k_score<<<gth_grid, 256, 0, stream>>>(hB, Wlin, sv, NN);
  k_pairs<<<(NP + 255) / 256, 256, 0, stream>>>(sv, Iidx, Jidx, blin, out, NP);
}

// Round 4
// 625.186 us; speedup vs baseline: 2.6960x; 1.0724x over previous
//
#include <hip/hip_runtime.h>
#include <hip/hip_bf16.h>
#include <math.h>

#define NN 100000
#define NE 1600000
#define NP 500000
#define HD 128
#define SCAN_ELEMS 1024
#define NBLK 98                    // ceil(NN/1024)
#define NPAD (NBLK * SCAN_ELEMS)   // 100352

// ---- bf16 helpers (bit-level, no header dependence in hot path) ----
__device__ __forceinline__ float bf_lo(unsigned int u) { return __uint_as_float(u << 16); }
__device__ __forceinline__ float bf_hi(unsigned int u) { return __uint_as_float(u & 0xffff0000u); }
__device__ __forceinline__ unsigned int pack_bf16x2(float a, float b) {
  unsigned int ua = __float_as_uint(a), ub = __float_as_uint(b);
  ua = (ua + 0x7fffu + ((ua >> 16) & 1u)) >> 16;   // RNE
  ub = (ub + 0x7fffu + ((ub >> 16) & 1u)) >> 16;
  return ua | (ub << 16);
}

// ---------------- CSR build ----------------
__global__ void k_zero_int(int* p, int n) {
  int i = blockIdx.x * 256 + threadIdx.x;
  if (i < n) p[i] = 0;
}

__global__ void k_count(const int* __restrict__ dst, int* __restrict__ cnt, int ne) {
  int e = blockIdx.x * 256 + threadIdx.x;
  if (e < ne) atomicAdd(cnt + dst[e], 1);
}

__global__ void k_dinv(const int* __restrict__ cnt, float* __restrict__ dinv, int n) {
  int i = blockIdx.x * 256 + threadIdx.x;
  if (i < n) dinv[i] = rsqrtf((float)cnt[i] + 1.0f);
}

__global__ __launch_bounds__(256) void k_scan1(const int* __restrict__ cnt,
                                               int* __restrict__ rowptr,
                                               int* __restrict__ bsum) {
  __shared__ int sh[256];
  const int t = threadIdx.x;
  const int base = blockIdx.x * SCAN_ELEMS + t * 4;
  int4 v = ((const int4*)cnt)[blockIdx.x * 256 + t];
  int s0 = v.x, s1 = s0 + v.y, s2 = s1 + v.z, s3 = s2 + v.w;
  sh[t] = s3;
  __syncthreads();
  int run = s3;
#pragma unroll
  for (int o = 1; o < 256; o <<= 1) {
    int add = (t >= o) ? sh[t - o] : 0;
    __syncthreads();
    sh[t] += add;
    __syncthreads();
  }
  int exc = sh[t] - run;
  if (base + 0 < NN) rowptr[base + 0] = exc;
  if (base + 1 < NN) rowptr[base + 1] = exc + s0;
  if (base + 2 < NN) rowptr[base + 2] = exc + s1;
  if (base + 3 < NN) rowptr[base + 3] = exc + s2;
  if (t == 255) bsum[blockIdx.x] = sh[255];
}

__global__ __launch_bounds__(128) void k_scan2(int* __restrict__ bsum) {
  __shared__ int sh[128];
  const int t = threadIdx.x;
  int v = (t < NBLK) ? bsum[t] : 0;
  sh[t] = v;
  __syncthreads();
#pragma unroll
  for (int o = 1; o < 128; o <<= 1) {
    int add = (t >= o) ? sh[t - o] : 0;
    __syncthreads();
    sh[t] += add;
    __syncthreads();
  }
  if (t < NBLK) bsum[t] = sh[t] - v;
}

__global__ __launch_bounds__(256) void k_scan3(int* __restrict__ rowptr,
                                               int* __restrict__ cursor,
                                               const int* __restrict__ bsum) {
  const int t = threadIdx.x;
  const int base = blockIdx.x * SCAN_ELEMS + t * 4;
  const int off = bsum[blockIdx.x];
#pragma unroll
  for (int k = 0; k < 4; ++k) {
    int i = base + k;
    if (i < NN) {
      int r = rowptr[i] + off;
      rowptr[i] = r;
      cursor[i] = r;
    }
  }
  if (blockIdx.x == 0 && t == 0) rowptr[NN] = NE;
}

__global__ void k_fillcsr(const int* __restrict__ src, const int* __restrict__ dst,
                          int* __restrict__ cursor, int* __restrict__ col, int ne) {
  int e = blockIdx.x * 256 + threadIdx.x;
  if (e < ne) {
    int pos = atomicAdd(cursor + dst[e], 1);
    col[pos] = src[e];
  }
}

// ---------------- GEMM: hs[n] = bf16( dinv[n] * act(X[n]) @ W ) ----------------
// k-step-4 inner loop: ds_read_b128 for X broadcast, 4x float4 W from L1/L2.
template <bool RELU>
__global__ __launch_bounds__(256) void k_gemm128(const float* __restrict__ X,
                                                 const float* __restrict__ W,
                                                 const float* __restrict__ dinv,
                                                 unsigned int* __restrict__ hs,
                                                 int nrows) {
  __shared__ float xs[64 * 128];  // 32 KB
  const int tid = threadIdx.x;
  const int row0 = blockIdx.x * 64;
  const int valid = min(64, nrows - row0);

  const float4* Xv = (const float4*)(X + (size_t)row0 * HD);
  float4* xsv = (float4*)xs;
#pragma unroll
  for (int it = 0; it < 8; ++it) {
    int idx = it * 256 + tid;       // float4 idx within tile
    int r = idx >> 5;
    float4 v = make_float4(0.f, 0.f, 0.f, 0.f);
    if (r < valid) v = Xv[idx];
    if (RELU) {
      v.x = fmaxf(v.x, 0.f); v.y = fmaxf(v.y, 0.f);
      v.z = fmaxf(v.z, 0.f); v.w = fmaxf(v.w, 0.f);
    }
    xsv[idx] = v;
  }
  __syncthreads();

  const int c4 = tid & 31;          // float4 column index
  const int rb = (tid >> 5) * 8;    // first of 8 rows
  float acc[8][4];
#pragma unroll
  for (int r = 0; r < 8; ++r)
#pragma unroll
    for (int c = 0; c < 4; ++c) acc[r][c] = 0.f;

  const float4* Wv = (const float4*)W;
  for (int k = 0; k < 128; k += 4) {
    float4 w0 = Wv[(k + 0) * 32 + c4];
    float4 w1 = Wv[(k + 1) * 32 + c4];
    float4 w2 = Wv[(k + 2) * 32 + c4];
    float4 w3 = Wv[(k + 3) * 32 + c4];
#pragma unroll
    for (int r = 0; r < 8; ++r) {
      float4 xv = *(const float4*)(xs + (rb + r) * HD + k);
      acc[r][0] += xv.x * w0.x + xv.y * w1.x + xv.z * w2.x + xv.w * w3.x;
      acc[r][1] += xv.x * w0.y + xv.y * w1.y + xv.z * w2.y + xv.w * w3.y;
      acc[r][2] += xv.x * w0.z + xv.y * w1.z + xv.z * w2.z + xv.w * w3.z;
      acc[r][3] += xv.x * w0.w + xv.y * w1.w + xv.z * w2.w + xv.w * w3.w;
    }
  }

#pragma unroll
  for (int r = 0; r < 8; ++r) {
    int row = row0 + rb + r;
    if (row < nrows) {
      float dr = dinv[row];
      uint2 o;
      o.x = pack_bf16x2(acc[r][0] * dr, acc[r][1] * dr);
      o.y = pack_bf16x2(acc[r][2] * dr, acc[r][3] * dr);
      ((uint2*)(hs + (size_t)row * 64))[c4] = o;
    }
  }
}

// ---------------- gather (conv1): out = dinv*(sum_nbr hs + hs_self) + b ----------------
// One wave per node; lane holds 2 features packed in one bf16x2 word.
__global__ __launch_bounds__(256) void k_gather1(const unsigned int* __restrict__ hs,
                                                 const float* __restrict__ dinv,
                                                 const int* __restrict__ rowptr,
                                                 const int* __restrict__ col,
                                                 const float* __restrict__ bias,
                                                 float* __restrict__ outp, int n) {
  int node = blockIdx.x * 4 + (threadIdx.x >> 6);
  int lane = threadIdx.x & 63;
  if (node >= n) return;
  int beg = rowptr[node], end = rowptr[node + 1];

  const unsigned int* base = hs + lane;
  unsigned int us = base[(size_t)node * 64];
  float ax = bf_lo(us), ay = bf_hi(us);
  int e = beg;
  for (; e + 3 < end; e += 4) {
    int s0 = col[e], s1 = col[e + 1], s2 = col[e + 2], s3 = col[e + 3];
    unsigned int u0 = base[(size_t)s0 * 64];
    unsigned int u1 = base[(size_t)s1 * 64];
    unsigned int u2 = base[(size_t)s2 * 64];
    unsigned int u3 = base[(size_t)s3 * 64];
    ax += (bf_lo(u0) + bf_lo(u1)) + (bf_lo(u2) + bf_lo(u3));
    ay += (bf_hi(u0) + bf_hi(u1)) + (bf_hi(u2) + bf_hi(u3));
  }
  for (; e < end; ++e) {
    unsigned int u = base[(size_t)col[e] * 64];
    ax += bf_lo(u); ay += bf_hi(u);
  }
  float di = dinv[node];
  float2 b = ((const float2*)bias)[lane];
  ((float2*)outp)[(size_t)node * 64 + lane] = make_float2(ax * di + b.x, ay * di + b.y);
}

// ---------------- gather (conv2) fused with scoring ----------------
// h2 stays in registers; writes s[2n], s[2n+1] only.
__global__ __launch_bounds__(256) void k_gather_score(const unsigned int* __restrict__ hs,
                                                      const float* __restrict__ dinv,
                                                      const int* __restrict__ rowptr,
                                                      const int* __restrict__ col,
                                                      const float* __restrict__ bias,
                                                      const float* __restrict__ Wl,
                                                      float* __restrict__ sv, int n) {
  int node = blockIdx.x * 4 + (threadIdx.x >> 6);
  int lane = threadIdx.x & 63;
  if (node >= n) return;
  int beg = rowptr[node], end = rowptr[node + 1];

  const unsigned int* base = hs + lane;
  unsigned int us = base[(size_t)node * 64];
  float ax = bf_lo(us), ay = bf_hi(us);
  int e = beg;
  for (; e + 3 < end; e += 4) {
    int s0 = col[e], s1 = col[e + 1], s2 = col[e + 2], s3 = col[e + 3];
    unsigned int u0 = base[(size_t)s0 * 64];
    unsigned int u1 = base[(size_t)s1 * 64];
    unsigned int u2 = base[(size_t)s2 * 64];
    unsigned int u3 = base[(size_t)s3 * 64];
    ax += (bf_lo(u0) + bf_lo(u1)) + (bf_lo(u2) + bf_lo(u3));
    ay += (bf_hi(u0) + bf_hi(u1)) + (bf_hi(u2) + bf_hi(u3));
  }
  for (; e < end; ++e) {
    unsigned int u = base[(size_t)col[e] * 64];
    ax += bf_lo(u); ay += bf_hi(u);
  }
  float di = dinv[node];
  float2 b = ((const float2*)bias)[lane];
  float h0 = ax * di + b.x;
  float h1 = ay * di + b.y;
  float2 wl1 = ((const float2*)Wl)[lane];
  float2 wl2 = ((const float2*)(Wl + HD))[lane];
  float p1 = h0 * wl1.x + h1 * wl1.y;
  float p2 = h0 * wl2.x + h1 * wl2.y;
#pragma unroll
  for (int o = 32; o > 0; o >>= 1) {
    p1 += __shfl_down(p1, o);
    p2 += __shfl_down(p2, o);
  }
  if (lane == 0) {
    sv[node * 2] = p1;
    sv[node * 2 + 1] = p2;
  }
}

// ---------------- pair outputs ----------------
__global__ void k_pairs(const float* __restrict__ s, const int* __restrict__ I,
                        const int* __restrict__ J, const float* __restrict__ blin,
                        float* __restrict__ out, int np) {
  int p = blockIdx.x * 256 + threadIdx.x;
  if (p < np) {
    float v = s[2 * I[p]] + s[2 * J[p] + 1] + blin[0];
    out[p] = 1.f / (1.f + __expf(-v));
  }
}

extern "C" void kernel_launch(void* const* d_in, const int* in_sizes, int n_in,
                              void* d_out, int out_size, void* d_ws, size_t ws_size,
                              hipStream_t stream) {
  const float* x     = (const float*)d_in[0];
  const int*   eidx  = (const int*)d_in[1];
  const int*   Iidx  = (const int*)d_in[2];
  const int*   Jidx  = (const int*)d_in[3];
  const float* W1    = (const float*)d_in[4];
  const float* b1    = (const float*)d_in[5];
  const float* W2    = (const float*)d_in[6];
  const float* b2    = (const float*)d_in[7];
  const float* Wlin  = (const float*)d_in[8];
  const float* blin  = (const float*)d_in[9];
  const int* src = eidx;
  const int* dst = eidx + NE;

  // workspace layout (all offsets 16B-aligned)
  float* ws   = (float*)d_ws;
  float* dinv = ws;                                  // 100000
  float* h1   = dinv + 100000;                       // NN*128 fp32
  float* sv   = h1 + (size_t)NN * HD;                // 200000
  unsigned int* hs = (unsigned int*)(sv + 200000);   // NN*64 bf16x2 (reused conv1/conv2)
  int* cnt    = (int*)(hs + (size_t)NN * 64);        // NPAD
  int* rowptr = cnt + NPAD;                          // NN+1 (pad 100004)
  int* cursor = rowptr + 100004;                     // NN
  int* col    = cursor + 100000;                     // NE
  int* bsum   = col + NE;                            // NBLK (pad 128)

  float* out = (float*)d_out;

  // ---- CSR build (reused by both convs) ----
  k_zero_int<<<(NPAD + 255) / 256, 256, 0, stream>>>(cnt, NPAD);
  k_count<<<(NE + 255) / 256, 256, 0, stream>>>(dst, cnt, NE);
  k_dinv<<<(NN + 255) / 256, 256, 0, stream>>>(cnt, dinv, NN);
  k_scan1<<<NBLK, 256, 0, stream>>>(cnt, rowptr, bsum);
  k_scan2<<<1, 128, 0, stream>>>(bsum);
  k_scan3<<<NBLK, 256, 0, stream>>>(rowptr, cursor, bsum);
  k_fillcsr<<<(NE + 255) / 256, 256, 0, stream>>>(src, dst, cursor, col, NE);

  const int gemm_grid = (NN + 63) / 64;
  const int gth_grid = (NN + 3) / 4;

  // conv1: hs = bf16(dinv * (x@W1)); h1 = dinv*(gather(hs)+hs_self) + b1
  k_gemm128<false><<<gemm_grid, 256, 0, stream>>>(x, W1, dinv, hs, NN);
  k_gather1<<<gth_grid, 256, 0, stream>>>(hs, dinv, rowptr, col, b1, h1, NN);

  // conv2: hs = bf16(dinv * (relu(h1)@W2)); score fused into gather
  k_gemm128<true><<<gemm_grid, 256, 0, stream>>>(h1, W2, dinv, hs, NN);
  k_gather_score<<<gth_grid, 256, 0, stream>>>(hs, dinv, rowptr, col, b2, Wlin, sv, NN);

  // pair outputs
  k_pairs<<<(NP + 255) / 256, 256, 0, stream>>>(sv, Iidx, Jidx, blin, out, NP);
}

// Round 5
// 563.428 us; speedup vs baseline: 2.9915x; 1.1096x over previous
//
#include <hip/hip_runtime.h>
#include <hip/hip_bf16.h>
#include <math.h>

#define NN 100000
#define NE 1600000
#define NP 500000
#define HD 128
#define SCAN_ELEMS 1024
#define NBLK 98                    // ceil(NN/1024)
#define NPAD (NBLK * SCAN_ELEMS)   // 100352
#define NPB 128                    // nodes per bucket (pow2)
#define NB 782                     // ceil(NN/NPB)
#define CHUNK 4096                 // edges per binA workgroup

// ---- bf16 helpers ----
__device__ __forceinline__ float bf_lo(unsigned int u) { return __uint_as_float(u << 16); }
__device__ __forceinline__ float bf_hi(unsigned int u) { return __uint_as_float(u & 0xffff0000u); }
__device__ __forceinline__ unsigned int pack_bf16x2(float a, float b) {
  unsigned int ua = __float_as_uint(a), ub = __float_as_uint(b);
  ua = (ua + 0x7fffu + ((ua >> 16) & 1u)) >> 16;   // RNE
  ub = (ub + 0x7fffu + ((ub >> 16) & 1u)) >> 16;
  return ua | (ub << 16);
}

// ---------------- CSR build ----------------
__global__ void k_zero_int(int* p, int n) {
  int i = blockIdx.x * 256 + threadIdx.x;
  if (i < n) p[i] = 0;
}

__global__ void k_count(const int* __restrict__ dst, int* __restrict__ cnt, int ne) {
  int e = blockIdx.x * 256 + threadIdx.x;
  if (e < ne) atomicAdd(cnt + dst[e], 1);
}

__global__ void k_dinv(const int* __restrict__ cnt, float* __restrict__ dinv, int n) {
  int i = blockIdx.x * 256 + threadIdx.x;
  if (i < n) dinv[i] = rsqrtf((float)cnt[i] + 1.0f);
}

__global__ __launch_bounds__(256) void k_scan1(const int* __restrict__ cnt,
                                               int* __restrict__ rowptr,
                                               int* __restrict__ bsum) {
  __shared__ int sh[256];
  const int t = threadIdx.x;
  const int base = blockIdx.x * SCAN_ELEMS + t * 4;
  int4 v = ((const int4*)cnt)[blockIdx.x * 256 + t];
  int s0 = v.x, s1 = s0 + v.y, s2 = s1 + v.z, s3 = s2 + v.w;
  sh[t] = s3;
  __syncthreads();
  int run = s3;
#pragma unroll
  for (int o = 1; o < 256; o <<= 1) {
    int add = (t >= o) ? sh[t - o] : 0;
    __syncthreads();
    sh[t] += add;
    __syncthreads();
  }
  int exc = sh[t] - run;
  if (base + 0 < NN) rowptr[base + 0] = exc;
  if (base + 1 < NN) rowptr[base + 1] = exc + s0;
  if (base + 2 < NN) rowptr[base + 2] = exc + s1;
  if (base + 3 < NN) rowptr[base + 3] = exc + s2;
  if (t == 255) bsum[blockIdx.x] = sh[255];
}

__global__ __launch_bounds__(128) void k_scan2(int* __restrict__ bsum) {
  __shared__ int sh[128];
  const int t = threadIdx.x;
  int v = (t < NBLK) ? bsum[t] : 0;
  sh[t] = v;
  __syncthreads();
#pragma unroll
  for (int o = 1; o < 128; o <<= 1) {
    int add = (t >= o) ? sh[t - o] : 0;
    __syncthreads();
    sh[t] += add;
    __syncthreads();
  }
  if (t < NBLK) bsum[t] = sh[t] - v;
}

__global__ __launch_bounds__(256) void k_scan3(int* __restrict__ rowptr,
                                               const int* __restrict__ bsum) {
  const int t = threadIdx.x;
  const int base = blockIdx.x * SCAN_ELEMS + t * 4;
  const int off = bsum[blockIdx.x];
#pragma unroll
  for (int k = 0; k < 4; ++k) {
    int i = base + k;
    if (i < NN) rowptr[i] += off;
  }
  if (blockIdx.x == 0 && t == 0) rowptr[NN] = NE;
}

// gcursor[b] = rowptr[min(b*NPB, NN)]
__global__ void k_initgcur(const int* __restrict__ rowptr, int* __restrict__ gcursor) {
  int b = blockIdx.x * 256 + threadIdx.x;
  if (b < NB) {
    int nd = b * NPB;
    gcursor[b] = rowptr[nd > NN ? NN : nd];
  }
}

// ---- binA: bin edges into per-bucket contiguous regions (8B entries) ----
__global__ __launch_bounds__(256) void k_binA(const int* __restrict__ src,
                                              const int* __restrict__ dst,
                                              int* __restrict__ gcursor,
                                              uint2* __restrict__ binned, int ne) {
  __shared__ int hist[NB];
  __shared__ int base[NB];
  const int t = threadIdx.x;
  const int e0 = blockIdx.x * CHUNK;

  for (int i = t; i < NB; i += 256) hist[i] = 0;
  __syncthreads();

#pragma unroll
  for (int k = 0; k < CHUNK / 256; ++k) {
    int e = e0 + k * 256 + t;
    if (e < ne) atomicAdd(&hist[dst[e] >> 7], 1);
  }
  __syncthreads();

  for (int i = t; i < NB; i += 256) {
    int c = hist[i];
    base[i] = c ? atomicAdd(&gcursor[i], c) : 0;
    hist[i] = 0;
  }
  __syncthreads();

#pragma unroll
  for (int k = 0; k < CHUNK / 256; ++k) {
    int e = e0 + k * 256 + t;
    if (e < ne) {
      int d = dst[e];
      int b = d >> 7;
      int pos = base[b] + atomicAdd(&hist[b], 1);
      binned[pos] = make_uint2((unsigned int)src[e], (unsigned int)d);
    }
  }
}

// ---- binB: exact CSR placement within each bucket (localized writes) ----
__global__ __launch_bounds__(256) void k_binB(const uint2* __restrict__ binned,
                                              const int* __restrict__ rowptr,
                                              int* __restrict__ col) {
  __shared__ int lcur[NPB];
  const int b = blockIdx.x;
  const int t = threadIdx.x;
  const int node0 = b * NPB;
  const int node1 = (node0 + NPB > NN) ? NN : node0 + NPB;
  const int nnode = node1 - node0;
  if (t < nnode) lcur[t] = rowptr[node0 + t];
  __syncthreads();
  const int gbase = rowptr[node0];
  const int gend = rowptr[node1];
  for (int i = gbase + t; i < gend; i += 256) {
    uint2 p = binned[i];
    int pos = atomicAdd(&lcur[p.y - node0], 1);
    col[pos] = (int)p.x;
  }
}

// ---------------- GEMM: hs[n] = bf16( dinv[n] * act(X[n]) @ W ) ----------------
template <bool RELU>
__global__ __launch_bounds__(256) void k_gemm128(const float* __restrict__ X,
                                                 const float* __restrict__ W,
                                                 const float* __restrict__ dinv,
                                                 unsigned int* __restrict__ hs,
                                                 int nrows) {
  __shared__ float xs[64 * 128];  // 32 KB
  const int tid = threadIdx.x;
  const int row0 = blockIdx.x * 64;
  const int valid = min(64, nrows - row0);

  const float4* Xv = (const float4*)(X + (size_t)row0 * HD);
  float4* xsv = (float4*)xs;
#pragma unroll
  for (int it = 0; it < 8; ++it) {
    int idx = it * 256 + tid;
    int r = idx >> 5;
    float4 v = make_float4(0.f, 0.f, 0.f, 0.f);
    if (r < valid) v = Xv[idx];
    if (RELU) {
      v.x = fmaxf(v.x, 0.f); v.y = fmaxf(v.y, 0.f);
      v.z = fmaxf(v.z, 0.f); v.w = fmaxf(v.w, 0.f);
    }
    xsv[idx] = v;
  }
  __syncthreads();

  const int c4 = tid & 31;
  const int rb = (tid >> 5) * 8;
  float acc[8][4];
#pragma unroll
  for (int r = 0; r < 8; ++r)
#pragma unroll
    for (int c = 0; c < 4; ++c) acc[r][c] = 0.f;

  const float4* Wv = (const float4*)W;
  for (int k = 0; k < 128; k += 4) {
    float4 w0 = Wv[(k + 0) * 32 + c4];
    float4 w1 = Wv[(k + 1) * 32 + c4];
    float4 w2 = Wv[(k + 2) * 32 + c4];
    float4 w3 = Wv[(k + 3) * 32 + c4];
#pragma unroll
    for (int r = 0; r < 8; ++r) {
      float4 xv = *(const float4*)(xs + (rb + r) * HD + k);
      acc[r][0] += xv.x * w0.x + xv.y * w1.x + xv.z * w2.x + xv.w * w3.x;
      acc[r][1] += xv.x * w0.y + xv.y * w1.y + xv.z * w2.y + xv.w * w3.y;
      acc[r][2] += xv.x * w0.z + xv.y * w1.z + xv.z * w2.z + xv.w * w3.z;
      acc[r][3] += xv.x * w0.w + xv.y * w1.w + xv.z * w2.w + xv.w * w3.w;
    }
  }

#pragma unroll
  for (int r = 0; r < 8; ++r) {
    int row = row0 + rb + r;
    if (row < nrows) {
      float dr = dinv[row];
      uint2 o;
      o.x = pack_bf16x2(acc[r][0] * dr, acc[r][1] * dr);
      o.y = pack_bf16x2(acc[r][2] * dr, acc[r][3] * dr);
      ((uint2*)(hs + (size_t)row * 64))[c4] = o;
    }
  }
}

// ---------------- gather (conv1) ----------------
__global__ __launch_bounds__(256) void k_gather1(const unsigned int* __restrict__ hs,
                                                 const float* __restrict__ dinv,
                                                 const int* __restrict__ rowptr,
                                                 const int* __restrict__ col,
                                                 const float* __restrict__ bias,
                                                 float* __restrict__ outp, int n) {
  int node = blockIdx.x * 4 + (threadIdx.x >> 6);
  int lane = threadIdx.x & 63;
  if (node >= n) return;
  int beg = rowptr[node], end = rowptr[node + 1];

  const unsigned int* base = hs + lane;
  unsigned int us = base[(size_t)node * 64];
  float ax = bf_lo(us), ay = bf_hi(us);
  int e = beg;
  for (; e + 3 < end; e += 4) {
    int s0 = col[e], s1 = col[e + 1], s2 = col[e + 2], s3 = col[e + 3];
    unsigned int u0 = base[(size_t)s0 * 64];
    unsigned int u1 = base[(size_t)s1 * 64];
    unsigned int u2 = base[(size_t)s2 * 64];
    unsigned int u3 = base[(size_t)s3 * 64];
    ax += (bf_lo(u0) + bf_lo(u1)) + (bf_lo(u2) + bf_lo(u3));
    ay += (bf_hi(u0) + bf_hi(u1)) + (bf_hi(u2) + bf_hi(u3));
  }
  for (; e < end; ++e) {
    unsigned int u = base[(size_t)col[e] * 64];
    ax += bf_lo(u); ay += bf_hi(u);
  }
  float di = dinv[node];
  float2 b = ((const float2*)bias)[lane];
  ((float2*)outp)[(size_t)node * 64 + lane] = make_float2(ax * di + b.x, ay * di + b.y);
}

// ---------------- gather (conv2) fused with scoring ----------------
__global__ __launch_bounds__(256) void k_gather_score(const unsigned int* __restrict__ hs,
                                                      const float* __restrict__ dinv,
                                                      const int* __restrict__ rowptr,
                                                      const int* __restrict__ col,
                                                      const float* __restrict__ bias,
                                                      const float* __restrict__ Wl,
                                                      float* __restrict__ sv, int n) {
  int node = blockIdx.x * 4 + (threadIdx.x >> 6);
  int lane = threadIdx.x & 63;
  if (node >= n) return;
  int beg = rowptr[node], end = rowptr[node + 1];

  const unsigned int* base = hs + lane;
  unsigned int us = base[(size_t)node * 64];
  float ax = bf_lo(us), ay = bf_hi(us);
  int e = beg;
  for (; e + 3 < end; e += 4) {
    int s0 = col[e], s1 = col[e + 1], s2 = col[e + 2], s3 = col[e + 3];
    unsigned int u0 = base[(size_t)s0 * 64];
    unsigned int u1 = base[(size_t)s1 * 64];
    unsigned int u2 = base[(size_t)s2 * 64];
    unsigned int u3 = base[(size_t)s3 * 64];
    ax += (bf_lo(u0) + bf_lo(u1)) + (bf_lo(u2) + bf_lo(u3));
    ay += (bf_hi(u0) + bf_hi(u1)) + (bf_hi(u2) + bf_hi(u3));
  }
  for (; e < end; ++e) {
    unsigned int u = base[(size_t)col[e] * 64];
    ax += bf_lo(u); ay += bf_hi(u);
  }
  float di = dinv[node];
  float2 b = ((const float2*)bias)[lane];
  float h0 = ax * di + b.x;
  float h1 = ay * di + b.y;
  float2 wl1 = ((const float2*)Wl)[lane];
  float2 wl2 = ((const float2*)(Wl + HD))[lane];
  float p1 = h0 * wl1.x + h1 * wl1.y;
  float p2 = h0 * wl2.x + h1 * wl2.y;
#pragma unroll
  for (int o = 32; o > 0; o >>= 1) {
    p1 += __shfl_down(p1, o);
    p2 += __shfl_down(p2, o);
  }
  if (lane == 0) {
    sv[node * 2] = p1;
    sv[node * 2 + 1] = p2;
  }
}

// ---------------- pair outputs ----------------
__global__ void k_pairs(const float* __restrict__ s, const int* __restrict__ I,
                        const int* __restrict__ J, const float* __restrict__ blin,
                        float* __restrict__ out, int np) {
  int p = blockIdx.x * 256 + threadIdx.x;
  if (p < np) {
    float v = s[2 * I[p]] + s[2 * J[p] + 1] + blin[0];
    out[p] = 1.f / (1.f + __expf(-v));
  }
}

extern "C" void kernel_launch(void* const* d_in, const int* in_sizes, int n_in,
                              void* d_out, int out_size, void* d_ws, size_t ws_size,
                              hipStream_t stream) {
  const float* x     = (const float*)d_in[0];
  const int*   eidx  = (const int*)d_in[1];
  const int*   Iidx  = (const int*)d_in[2];
  const int*   Jidx  = (const int*)d_in[3];
  const float* W1    = (const float*)d_in[4];
  const float* b1    = (const float*)d_in[5];
  const float* W2    = (const float*)d_in[6];
  const float* b2    = (const float*)d_in[7];
  const float* Wlin  = (const float*)d_in[8];
  const float* blin  = (const float*)d_in[9];
  const int* src = eidx;
  const int* dst = eidx + NE;

  // workspace layout (all offsets 16B-aligned)
  float* ws   = (float*)d_ws;
  float* dinv = ws;                                  // 100000
  float* h1   = dinv + 100000;                       // NN*128 fp32
  float* sv   = h1 + (size_t)NN * HD;                // 200000
  unsigned int* hs = (unsigned int*)(sv + 200000);   // NN*64 bf16x2
  int* cnt    = (int*)(hs + (size_t)NN * 64);        // NPAD
  int* rowptr = cnt + NPAD;                          // NN+1 (pad 100004)
  int* col    = rowptr + 100004;                     // NE
  int* bsum   = col + NE;                            // NBLK (pad 128)
  int* gcursor= bsum + 128;                          // NB (pad 784)
  uint2* binned = (uint2*)(gcursor + 784);           // NE x 8B (8B-aligned: offset even)

  float* out = (float*)d_out;

  // ---- CSR build ----
  k_zero_int<<<(NPAD + 255) / 256, 256, 0, stream>>>(cnt, NPAD);
  k_count<<<(NE + 255) / 256, 256, 0, stream>>>(dst, cnt, NE);
  k_dinv<<<(NN + 255) / 256, 256, 0, stream>>>(cnt, dinv, NN);
  k_scan1<<<NBLK, 256, 0, stream>>>(cnt, rowptr, bsum);
  k_scan2<<<1, 128, 0, stream>>>(bsum);
  k_scan3<<<NBLK, 256, 0, stream>>>(rowptr, bsum);
  k_initgcur<<<(NB + 255) / 256, 256, 0, stream>>>(rowptr, gcursor);
  k_binA<<<(NE + CHUNK - 1) / CHUNK, 256, 0, stream>>>(src, dst, gcursor, binned, NE);
  k_binB<<<NB, 256, 0, stream>>>(binned, rowptr, col);

  const int gemm_grid = (NN + 63) / 64;
  const int gth_grid = (NN + 3) / 4;

  // conv1
  k_gemm128<false><<<gemm_grid, 256, 0, stream>>>(x, W1, dinv, hs, NN);
  k_gather1<<<gth_grid, 256, 0, stream>>>(hs, dinv, rowptr, col, b1, h1, NN);

  // conv2 (score fused)
  k_gemm128<true><<<gemm_grid, 256, 0, stream>>>(h1, W2, dinv, hs, NN);
  k_gather_score<<<gth_grid, 256, 0, stream>>>(hs, dinv, rowptr, col, b2, Wlin, sv, NN);

  // pair outputs
  k_pairs<<<(NP + 255) / 256, 256, 0, stream>>>(sv, Iidx, Jidx, blin, out, NP);
}

// Round 6
// 458.618 us; speedup vs baseline: 3.6752x; 1.2285x over previous
//
#include <hip/hip_runtime.h>
#include <hip/hip_bf16.h>
#include <math.h>

#define NN 100000
#define NE 1600000
#define NP 500000
#define HD 128
#define SCAN_ELEMS 1024
#define NBLK 98                    // ceil(NN/1024)
#define NPAD (NBLK * SCAN_ELEMS)   // 100352
#define NPB 128                    // nodes per bucket (pow2)
#define NB 782                     // ceil(NN/NPB)
#define CHUNK 4096                 // edges per binA workgroup

typedef __attribute__((ext_vector_type(8))) short short8;   // 8 bf16 = 4 VGPRs
typedef __attribute__((ext_vector_type(4))) float f32x4;

// ---- bf16 helpers ----
__device__ __forceinline__ float bf_lo(unsigned int u) { return __uint_as_float(u << 16); }
__device__ __forceinline__ float bf_hi(unsigned int u) { return __uint_as_float(u & 0xffff0000u); }
__device__ __forceinline__ unsigned short bf16_rne(float f) {
  unsigned int u = __float_as_uint(f);
  u = (u + 0x7fffu + ((u >> 16) & 1u)) >> 16;
  return (unsigned short)u;
}
__device__ __forceinline__ unsigned int pack_bf16x2(float a, float b) {
  return (unsigned int)bf16_rne(a) | ((unsigned int)bf16_rne(b) << 16);
}

// ---------------- CSR build ----------------
__global__ void k_zero_int(int* p, int n) {
  int i = blockIdx.x * 256 + threadIdx.x;
  if (i < n) p[i] = 0;
}

__global__ void k_count(const int* __restrict__ dst, int* __restrict__ cnt, int ne) {
  int e = blockIdx.x * 256 + threadIdx.x;
  if (e < ne) atomicAdd(cnt + dst[e], 1);
}

__global__ void k_dinv(const int* __restrict__ cnt, float* __restrict__ dinv, int n) {
  int i = blockIdx.x * 256 + threadIdx.x;
  if (i < n) dinv[i] = rsqrtf((float)cnt[i] + 1.0f);
}

__global__ __launch_bounds__(256) void k_scan1(const int* __restrict__ cnt,
                                               int* __restrict__ rowptr,
                                               int* __restrict__ bsum) {
  __shared__ int sh[256];
  const int t = threadIdx.x;
  const int base = blockIdx.x * SCAN_ELEMS + t * 4;
  int4 v = ((const int4*)cnt)[blockIdx.x * 256 + t];
  int s0 = v.x, s1 = s0 + v.y, s2 = s1 + v.z, s3 = s2 + v.w;
  sh[t] = s3;
  __syncthreads();
  int run = s3;
#pragma unroll
  for (int o = 1; o < 256; o <<= 1) {
    int add = (t >= o) ? sh[t - o] : 0;
    __syncthreads();
    sh[t] += add;
    __syncthreads();
  }
  int exc = sh[t] - run;
  if (base + 0 < NN) rowptr[base + 0] = exc;
  if (base + 1 < NN) rowptr[base + 1] = exc + s0;
  if (base + 2 < NN) rowptr[base + 2] = exc + s1;
  if (base + 3 < NN) rowptr[base + 3] = exc + s2;
  if (t == 255) bsum[blockIdx.x] = sh[255];
}

__global__ __launch_bounds__(128) void k_scan2(int* __restrict__ bsum) {
  __shared__ int sh[128];
  const int t = threadIdx.x;
  int v = (t < NBLK) ? bsum[t] : 0;
  sh[t] = v;
  __syncthreads();
#pragma unroll
  for (int o = 1; o < 128; o <<= 1) {
    int add = (t >= o) ? sh[t - o] : 0;
    __syncthreads();
    sh[t] += add;
    __syncthreads();
  }
  if (t < NBLK) bsum[t] = sh[t] - v;
}

__global__ __launch_bounds__(256) void k_scan3(int* __restrict__ rowptr,
                                               const int* __restrict__ bsum) {
  const int t = threadIdx.x;
  const int base = blockIdx.x * SCAN_ELEMS + t * 4;
  const int off = bsum[blockIdx.x];
#pragma unroll
  for (int k = 0; k < 4; ++k) {
    int i = base + k;
    if (i < NN) rowptr[i] += off;
  }
  if (blockIdx.x == 0 && t == 0) rowptr[NN] = NE;
}

__global__ void k_initgcur(const int* __restrict__ rowptr, int* __restrict__ gcursor) {
  int b = blockIdx.x * 256 + threadIdx.x;
  if (b < NB) {
    int nd = b * NPB;
    gcursor[b] = rowptr[nd > NN ? NN : nd];
  }
}

// ---- binA: bin edges into per-bucket contiguous regions (8B entries) ----
__global__ __launch_bounds__(256) void k_binA(const int* __restrict__ src,
                                              const int* __restrict__ dst,
                                              int* __restrict__ gcursor,
                                              uint2* __restrict__ binned, int ne) {
  __shared__ int hist[NB];
  __shared__ int base[NB];
  const int t = threadIdx.x;
  const int e0 = blockIdx.x * CHUNK;

  for (int i = t; i < NB; i += 256) hist[i] = 0;
  __syncthreads();

#pragma unroll
  for (int k = 0; k < CHUNK / 256; ++k) {
    int e = e0 + k * 256 + t;
    if (e < ne) atomicAdd(&hist[dst[e] >> 7], 1);
  }
  __syncthreads();

  for (int i = t; i < NB; i += 256) {
    int c = hist[i];
    base[i] = c ? atomicAdd(&gcursor[i], c) : 0;
    hist[i] = 0;
  }
  __syncthreads();

#pragma unroll
  for (int k = 0; k < CHUNK / 256; ++k) {
    int e = e0 + k * 256 + t;
    if (e < ne) {
      int d = dst[e];
      int b = d >> 7;
      int pos = base[b] + atomicAdd(&hist[b], 1);
      binned[pos] = make_uint2((unsigned int)src[e], (unsigned int)d);
    }
  }
}

// ---- binB: exact CSR placement within each bucket ----
__global__ __launch_bounds__(256) void k_binB(const uint2* __restrict__ binned,
                                              const int* __restrict__ rowptr,
                                              int* __restrict__ col) {
  __shared__ int lcur[NPB];
  const int b = blockIdx.x;
  const int t = threadIdx.x;
  const int node0 = b * NPB;
  const int node1 = (node0 + NPB > NN) ? NN : node0 + NPB;
  const int nnode = node1 - node0;
  if (t < nnode) lcur[t] = rowptr[node0 + t];
  __syncthreads();
  const int gbase = rowptr[node0];
  const int gend = rowptr[node1];
  for (int i = gbase + t; i < gend; i += 256) {
    uint2 p = binned[i];
    int pos = atomicAdd(&lcur[p.y - node0], 1);
    col[pos] = (int)p.x;
  }
}

// ---------------- W transpose+cast: Wt[n][k] = bf16(W[k][n]) ----------------
__global__ void k_wconv(const float* __restrict__ W, unsigned short* __restrict__ Wt) {
  int t = blockIdx.x * 256 + threadIdx.x;  // 16384
  int n = t >> 7, k = t & 127;
  Wt[t] = bf16_rne(W[k * HD + n]);
}

// ---------------- MFMA GEMM: hs[n][c] = bf16( dinv[n] * (X @ W)[n][c] ) ----------------
// One wave per 16 rows; 8 n-tiles of 16 cols; K=128 in 4 chunks of 32.
// A-frag: lane holds A[m=lane&15][k=quad*8+j]; B-frag: B[k=quad*8+j][n=lane&15]
// (Wt[n][k] row-major makes B-frag a contiguous 16B load).
// C/D: col=lane&15, row=quad*4+reg  [m89-verified layouts].
template <bool SRC_BF16>
__global__ __launch_bounds__(256) void k_gemm_mfma(const void* __restrict__ Xsrc,
                                                   const unsigned short* __restrict__ Wt,
                                                   const float* __restrict__ dinv,
                                                   unsigned short* __restrict__ hs,
                                                   int nrows) {
  const int wave = threadIdx.x >> 6;
  const int lane = threadIdx.x & 63;
  const int row0 = blockIdx.x * 64 + wave * 16;
  if (row0 >= nrows) return;
  const int lm = lane & 15;   // A-row / C-col
  const int lq = lane >> 4;   // quad

  int arow = row0 + lm;
  int arowc = arow < nrows ? arow : nrows - 1;  // clamp (stores are guarded)

  short8 afrag[4];
  if (SRC_BF16) {
    const unsigned short* X = (const unsigned short*)Xsrc;
#pragma unroll
    for (int kc = 0; kc < 4; ++kc) {
      int k0 = kc * 32 + lq * 8;
      afrag[kc] = *(const short8*)(X + (size_t)arowc * HD + k0);
    }
  } else {
    const float* X = (const float*)Xsrc;
#pragma unroll
    for (int kc = 0; kc < 4; ++kc) {
      int k0 = kc * 32 + lq * 8;
      const float4* p = (const float4*)(X + (size_t)arowc * HD + k0);
      float4 f0 = p[0], f1 = p[1];
      short8 a;
      a[0] = (short)bf16_rne(f0.x); a[1] = (short)bf16_rne(f0.y);
      a[2] = (short)bf16_rne(f0.z); a[3] = (short)bf16_rne(f0.w);
      a[4] = (short)bf16_rne(f1.x); a[5] = (short)bf16_rne(f1.y);
      a[6] = (short)bf16_rne(f1.z); a[7] = (short)bf16_rne(f1.w);
      afrag[kc] = a;
    }
  }

  float dv[4];
#pragma unroll
  for (int r = 0; r < 4; ++r) {
    int row = row0 + lq * 4 + r;
    dv[r] = dinv[row < nrows ? row : 0];
  }

#pragma unroll
  for (int nt = 0; nt < 8; ++nt) {
    f32x4 acc = {0.f, 0.f, 0.f, 0.f};
    const unsigned short* Wb = Wt + (size_t)(nt * 16 + lm) * HD + lq * 8;
#pragma unroll
    for (int kc = 0; kc < 4; ++kc) {
      short8 bfrag = *(const short8*)(Wb + kc * 32);
      acc = __builtin_amdgcn_mfma_f32_16x16x32_bf16(afrag[kc], bfrag, acc, 0, 0, 0);
    }
#pragma unroll
    for (int r = 0; r < 4; ++r) {
      int row = row0 + lq * 4 + r;
      if (row < nrows)
        hs[(size_t)row * HD + nt * 16 + lm] = bf16_rne(acc[r] * dv[r]);
    }
  }
}

// ---------------- gather (conv1): h1b = bf16(relu(dinv*(sum+self)+b)) ----------------
__global__ __launch_bounds__(256) void k_gather1(const unsigned int* __restrict__ hs,
                                                 const float* __restrict__ dinv,
                                                 const int* __restrict__ rowptr,
                                                 const int* __restrict__ col,
                                                 const float* __restrict__ bias,
                                                 unsigned int* __restrict__ outp, int n) {
  int node = blockIdx.x * 4 + (threadIdx.x >> 6);
  int lane = threadIdx.x & 63;
  if (node >= n) return;
  int beg = rowptr[node], end = rowptr[node + 1];

  const unsigned int* base = hs + lane;
  unsigned int us = base[(size_t)node * 64];
  float ax = bf_lo(us), ay = bf_hi(us);
  int e = beg;
  for (; e + 3 < end; e += 4) {
    int s0 = col[e], s1 = col[e + 1], s2 = col[e + 2], s3 = col[e + 3];
    unsigned int u0 = base[(size_t)s0 * 64];
    unsigned int u1 = base[(size_t)s1 * 64];
    unsigned int u2 = base[(size_t)s2 * 64];
    unsigned int u3 = base[(size_t)s3 * 64];
    ax += (bf_lo(u0) + bf_lo(u1)) + (bf_lo(u2) + bf_lo(u3));
    ay += (bf_hi(u0) + bf_hi(u1)) + (bf_hi(u2) + bf_hi(u3));
  }
  for (; e < end; ++e) {
    unsigned int u = base[(size_t)col[e] * 64];
    ax += bf_lo(u); ay += bf_hi(u);
  }
  float di = dinv[node];
  float2 b = ((const float2*)bias)[lane];
  float h0 = fmaxf(ax * di + b.x, 0.f);
  float h1 = fmaxf(ay * di + b.y, 0.f);
  outp[(size_t)node * 64 + lane] = pack_bf16x2(h0, h1);
}

// ---------------- gather (conv2) fused with scoring ----------------
__global__ __launch_bounds__(256) void k_gather_score(const unsigned int* __restrict__ hs,
                                                      const float* __restrict__ dinv,
                                                      const int* __restrict__ rowptr,
                                                      const int* __restrict__ col,
                                                      const float* __restrict__ bias,
                                                      const float* __restrict__ Wl,
                                                      float* __restrict__ sv, int n) {
  int node = blockIdx.x * 4 + (threadIdx.x >> 6);
  int lane = threadIdx.x & 63;
  if (node >= n) return;
  int beg = rowptr[node], end = rowptr[node + 1];

  const unsigned int* base = hs + lane;
  unsigned int us = base[(size_t)node * 64];
  float ax = bf_lo(us), ay = bf_hi(us);
  int e = beg;
  for (; e + 3 < end; e += 4) {
    int s0 = col[e], s1 = col[e + 1], s2 = col[e + 2], s3 = col[e + 3];
    unsigned int u0 = base[(size_t)s0 * 64];
    unsigned int u1 = base[(size_t)s1 * 64];
    unsigned int u2 = base[(size_t)s2 * 64];
    unsigned int u3 = base[(size_t)s3 * 64];
    ax += (bf_lo(u0) + bf_lo(u1)) + (bf_lo(u2) + bf_lo(u3));
    ay += (bf_hi(u0) + bf_hi(u1)) + (bf_hi(u2) + bf_hi(u3));
  }
  for (; e < end; ++e) {
    unsigned int u = base[(size_t)col[e] * 64];
    ax += bf_lo(u); ay += bf_hi(u);
  }
  float di = dinv[node];
  float2 b = ((const float2*)bias)[lane];
  float h0 = ax * di + b.x;
  float h1 = ay * di + b.y;
  float2 wl1 = ((const float2*)Wl)[lane];
  float2 wl2 = ((const float2*)(Wl + HD))[lane];
  float p1 = h0 * wl1.x + h1 * wl1.y;
  float p2 = h0 * wl2.x + h1 * wl2.y;
#pragma unroll
  for (int o = 32; o > 0; o >>= 1) {
    p1 += __shfl_down(p1, o);
    p2 += __shfl_down(p2, o);
  }
  if (lane == 0) {
    sv[node * 2] = p1;
    sv[node * 2 + 1] = p2;
  }
}

// ---------------- pair outputs ----------------
__global__ void k_pairs(const float* __restrict__ s, const int* __restrict__ I,
                        const int* __restrict__ J, const float* __restrict__ blin,
                        float* __restrict__ out, int np) {
  int p = blockIdx.x * 256 + threadIdx.x;
  if (p < np) {
    float v = s[2 * I[p]] + s[2 * J[p] + 1] + blin[0];
    out[p] = 1.f / (1.f + __expf(-v));
  }
}

extern "C" void kernel_launch(void* const* d_in, const int* in_sizes, int n_in,
                              void* d_out, int out_size, void* d_ws, size_t ws_size,
                              hipStream_t stream) {
  const float* x     = (const float*)d_in[0];
  const int*   eidx  = (const int*)d_in[1];
  const int*   Iidx  = (const int*)d_in[2];
  const int*   Jidx  = (const int*)d_in[3];
  const float* W1    = (const float*)d_in[4];
  const float* b1    = (const float*)d_in[5];
  const float* W2    = (const float*)d_in[6];
  const float* b2    = (const float*)d_in[7];
  const float* Wlin  = (const float*)d_in[8];
  const float* blin  = (const float*)d_in[9];
  const int* src = eidx;
  const int* dst = eidx + NE;

  // workspace layout (all offsets 16B-aligned)
  float* ws   = (float*)d_ws;
  float* dinv = ws;                                   // 100000
  float* sv   = dinv + 100000;                        // 200000
  unsigned int* hs  = (unsigned int*)(sv + 200000);   // NN*64 (bf16x2)
  unsigned int* h1b = hs + (size_t)NN * 64;           // NN*64 (bf16x2, relu'd)
  unsigned short* wt1 = (unsigned short*)(h1b + (size_t)NN * 64);  // 16384 bf16
  unsigned short* wt2 = wt1 + 16384;                  // 16384 bf16
  int* cnt    = (int*)(wt2 + 16384);                  // NPAD
  int* rowptr = cnt + NPAD;                           // NN+1 (pad 100004)
  int* col    = rowptr + 100004;                      // NE
  int* bsum   = col + NE;                             // 128
  int* gcursor= bsum + 128;                           // 784
  uint2* binned = (uint2*)(gcursor + 784);            // NE x 8B

  float* out = (float*)d_out;

  // ---- CSR build ----
  k_zero_int<<<(NPAD + 255) / 256, 256, 0, stream>>>(cnt, NPAD);
  k_count<<<(NE + 255) / 256, 256, 0, stream>>>(dst, cnt, NE);
  k_dinv<<<(NN + 255) / 256, 256, 0, stream>>>(cnt, dinv, NN);
  k_scan1<<<NBLK, 256, 0, stream>>>(cnt, rowptr, bsum);
  k_scan2<<<1, 128, 0, stream>>>(bsum);
  k_scan3<<<NBLK, 256, 0, stream>>>(rowptr, bsum);
  k_initgcur<<<(NB + 255) / 256, 256, 0, stream>>>(rowptr, gcursor);
  k_binA<<<(NE + CHUNK - 1) / CHUNK, 256, 0, stream>>>(src, dst, gcursor, binned, NE);
  k_binB<<<NB, 256, 0, stream>>>(binned, rowptr, col);

  // ---- weight prep ----
  k_wconv<<<64, 256, 0, stream>>>(W1, wt1);
  k_wconv<<<64, 256, 0, stream>>>(W2, wt2);

  const int gemm_grid = (NN + 63) / 64;
  const int gth_grid = (NN + 3) / 4;

  // conv1: hs = bf16(dinv*(x@W1)); h1b = bf16(relu(gather))
  k_gemm_mfma<false><<<gemm_grid, 256, 0, stream>>>(x, wt1, dinv, (unsigned short*)hs, NN);
  k_gather1<<<gth_grid, 256, 0, stream>>>(hs, dinv, rowptr, col, b1, h1b, NN);

  // conv2: hs = bf16(dinv*(h1b@W2)); score fused into gather
  k_gemm_mfma<true><<<gemm_grid, 256, 0, stream>>>(h1b, wt2, dinv, (unsigned short*)hs, NN);
  k_gather_score<<<gth_grid, 256, 0, stream>>>(hs, dinv, rowptr, col, b2, Wlin, sv, NN);

  // pair outputs
  k_pairs<<<(NP + 255) / 256, 256, 0, stream>>>(sv, Iidx, Jidx, blin, out, NP);
}

// Round 7
// 425.062 us; speedup vs baseline: 3.9653x; 1.0789x over previous
//
#include <hip/hip_runtime.h>
#include <hip/hip_bf16.h>
#include <math.h>

#define NN 100000
#define NE 1600000
#define NP 500000
#define HD 128
#define SCAN_ELEMS 1024
#define NBLK 98                    // ceil(NN/1024)
#define NPAD (NBLK * SCAN_ELEMS)   // 100352
#define NPB 128                    // nodes per bucket (pow2)
#define NB 782                     // ceil(NN/NPB)
#define CHUNK 4096                 // edges per binA workgroup

typedef __attribute__((ext_vector_type(8))) short short8;   // 8 bf16 = 4 VGPRs
typedef __attribute__((ext_vector_type(4))) float f32x4;

// ---- bf16 helpers ----
__device__ __forceinline__ float bf_lo(unsigned int u) { return __uint_as_float(u << 16); }
__device__ __forceinline__ float bf_hi(unsigned int u) { return __uint_as_float(u & 0xffff0000u); }
__device__ __forceinline__ unsigned short bf16_rne(float f) {
  unsigned int u = __float_as_uint(f);
  u = (u + 0x7fffu + ((u >> 16) & 1u)) >> 16;
  return (unsigned short)u;
}
__device__ __forceinline__ unsigned int pack_bf16x2(float a, float b) {
  return (unsigned int)bf16_rne(a) | ((unsigned int)bf16_rne(b) << 16);
}
__device__ __forceinline__ void acc_row(float* ax, uint4 u) {
  ax[0] += bf_lo(u.x); ax[1] += bf_hi(u.x);
  ax[2] += bf_lo(u.y); ax[3] += bf_hi(u.y);
  ax[4] += bf_lo(u.z); ax[5] += bf_hi(u.z);
  ax[6] += bf_lo(u.w); ax[7] += bf_hi(u.w);
}

// ---------------- CSR build ----------------
__global__ void k_zero_int(int* p, int n) {
  int i = blockIdx.x * 256 + threadIdx.x;
  if (i < n) p[i] = 0;
}

__global__ void k_count(const int* __restrict__ dst, int* __restrict__ cnt, int ne) {
  int e = blockIdx.x * 256 + threadIdx.x;
  if (e < ne) atomicAdd(cnt + dst[e], 1);
}

__global__ void k_dinv(const int* __restrict__ cnt, float* __restrict__ dinv, int n) {
  int i = blockIdx.x * 256 + threadIdx.x;
  if (i < n) dinv[i] = rsqrtf((float)cnt[i] + 1.0f);
}

__global__ __launch_bounds__(256) void k_scan1(const int* __restrict__ cnt,
                                               int* __restrict__ rowptr,
                                               int* __restrict__ bsum) {
  __shared__ int sh[256];
  const int t = threadIdx.x;
  const int base = blockIdx.x * SCAN_ELEMS + t * 4;
  int4 v = ((const int4*)cnt)[blockIdx.x * 256 + t];
  int s0 = v.x, s1 = s0 + v.y, s2 = s1 + v.z, s3 = s2 + v.w;
  sh[t] = s3;
  __syncthreads();
  int run = s3;
#pragma unroll
  for (int o = 1; o < 256; o <<= 1) {
    int add = (t >= o) ? sh[t - o] : 0;
    __syncthreads();
    sh[t] += add;
    __syncthreads();
  }
  int exc = sh[t] - run;
  if (base + 0 < NN) rowptr[base + 0] = exc;
  if (base + 1 < NN) rowptr[base + 1] = exc + s0;
  if (base + 2 < NN) rowptr[base + 2] = exc + s1;
  if (base + 3 < NN) rowptr[base + 3] = exc + s2;
  if (t == 255) bsum[blockIdx.x] = sh[255];
}

__global__ __launch_bounds__(128) void k_scan2(int* __restrict__ bsum) {
  __shared__ int sh[128];
  const int t = threadIdx.x;
  int v = (t < NBLK) ? bsum[t] : 0;
  sh[t] = v;
  __syncthreads();
#pragma unroll
  for (int o = 1; o < 128; o <<= 1) {
    int add = (t >= o) ? sh[t - o] : 0;
    __syncthreads();
    sh[t] += add;
    __syncthreads();
  }
  if (t < NBLK) bsum[t] = sh[t] - v;
}

__global__ __launch_bounds__(256) void k_scan3(int* __restrict__ rowptr,
                                               const int* __restrict__ bsum) {
  const int t = threadIdx.x;
  const int base = blockIdx.x * SCAN_ELEMS + t * 4;
  const int off = bsum[blockIdx.x];
#pragma unroll
  for (int k = 0; k < 4; ++k) {
    int i = base + k;
    if (i < NN) rowptr[i] += off;
  }
  if (blockIdx.x == 0 && t == 0) rowptr[NN] = NE;
}

__global__ void k_initgcur(const int* __restrict__ rowptr, int* __restrict__ gcursor) {
  int b = blockIdx.x * 256 + threadIdx.x;
  if (b < NB) {
    int nd = b * NPB;
    gcursor[b] = rowptr[nd > NN ? NN : nd];
  }
}

// ---- binA: bin edges into per-bucket contiguous regions (8B entries) ----
__global__ __launch_bounds__(256) void k_binA(const int* __restrict__ src,
                                              const int* __restrict__ dst,
                                              int* __restrict__ gcursor,
                                              uint2* __restrict__ binned, int ne) {
  __shared__ int hist[NB];
  __shared__ int base[NB];
  const int t = threadIdx.x;
  const int e0 = blockIdx.x * CHUNK;

  for (int i = t; i < NB; i += 256) hist[i] = 0;
  __syncthreads();

#pragma unroll
  for (int k = 0; k < CHUNK / 256; ++k) {
    int e = e0 + k * 256 + t;
    if (e < ne) atomicAdd(&hist[dst[e] >> 7], 1);
  }
  __syncthreads();

  for (int i = t; i < NB; i += 256) {
    int c = hist[i];
    base[i] = c ? atomicAdd(&gcursor[i], c) : 0;
    hist[i] = 0;
  }
  __syncthreads();

#pragma unroll
  for (int k = 0; k < CHUNK / 256; ++k) {
    int e = e0 + k * 256 + t;
    if (e < ne) {
      int d = dst[e];
      int b = d >> 7;
      int pos = base[b] + atomicAdd(&hist[b], 1);
      binned[pos] = make_uint2((unsigned int)src[e], (unsigned int)d);
    }
  }
}

// ---- binB: exact CSR placement within each bucket ----
__global__ __launch_bounds__(256) void k_binB(const uint2* __restrict__ binned,
                                              const int* __restrict__ rowptr,
                                              int* __restrict__ col) {
  __shared__ int lcur[NPB];
  const int b = blockIdx.x;
  const int t = threadIdx.x;
  const int node0 = b * NPB;
  const int node1 = (node0 + NPB > NN) ? NN : node0 + NPB;
  const int nnode = node1 - node0;
  if (t < nnode) lcur[t] = rowptr[node0 + t];
  __syncthreads();
  const int gbase = rowptr[node0];
  const int gend = rowptr[node1];
  for (int i = gbase + t; i < gend; i += 256) {
    uint2 p = binned[i];
    int pos = atomicAdd(&lcur[p.y - node0], 1);
    col[pos] = (int)p.x;
  }
}

// ---------------- W transpose+cast: Wt[n][k] = bf16(W[k][n]) ----------------
__global__ void k_wconv(const float* __restrict__ W, unsigned short* __restrict__ Wt) {
  int t = blockIdx.x * 256 + threadIdx.x;  // 16384
  int n = t >> 7, k = t & 127;
  Wt[t] = bf16_rne(W[k * HD + n]);
}

// ---------------- MFMA GEMM: hs[n][c] = bf16( dinv[n] * (X @ W)[n][c] ) ----------------
template <bool SRC_BF16>
__global__ __launch_bounds__(256) void k_gemm_mfma(const void* __restrict__ Xsrc,
                                                   const unsigned short* __restrict__ Wt,
                                                   const float* __restrict__ dinv,
                                                   unsigned short* __restrict__ hs,
                                                   int nrows) {
  const int wave = threadIdx.x >> 6;
  const int lane = threadIdx.x & 63;
  const int row0 = blockIdx.x * 64 + wave * 16;
  if (row0 >= nrows) return;
  const int lm = lane & 15;   // A-row / C-col
  const int lq = lane >> 4;   // quad

  int arow = row0 + lm;
  int arowc = arow < nrows ? arow : nrows - 1;  // clamp (stores are guarded)

  short8 afrag[4];
  if (SRC_BF16) {
    const unsigned short* X = (const unsigned short*)Xsrc;
#pragma unroll
    for (int kc = 0; kc < 4; ++kc) {
      int k0 = kc * 32 + lq * 8;
      afrag[kc] = *(const short8*)(X + (size_t)arowc * HD + k0);
    }
  } else {
    const float* X = (const float*)Xsrc;
#pragma unroll
    for (int kc = 0; kc < 4; ++kc) {
      int k0 = kc * 32 + lq * 8;
      const float4* p = (const float4*)(X + (size_t)arowc * HD + k0);
      float4 f0 = p[0], f1 = p[1];
      short8 a;
      a[0] = (short)bf16_rne(f0.x); a[1] = (short)bf16_rne(f0.y);
      a[2] = (short)bf16_rne(f0.z); a[3] = (short)bf16_rne(f0.w);
      a[4] = (short)bf16_rne(f1.x); a[5] = (short)bf16_rne(f1.y);
      a[6] = (short)bf16_rne(f1.z); a[7] = (short)bf16_rne(f1.w);
      afrag[kc] = a;
    }
  }

  float dv[4];
#pragma unroll
  for (int r = 0; r < 4; ++r) {
    int row = row0 + lq * 4 + r;
    dv[r] = dinv[row < nrows ? row : 0];
  }

#pragma unroll
  for (int nt = 0; nt < 8; ++nt) {
    f32x4 acc = {0.f, 0.f, 0.f, 0.f};
    const unsigned short* Wb = Wt + (size_t)(nt * 16 + lm) * HD + lq * 8;
#pragma unroll
    for (int kc = 0; kc < 4; ++kc) {
      short8 bfrag = *(const short8*)(Wb + kc * 32);
      acc = __builtin_amdgcn_mfma_f32_16x16x32_bf16(afrag[kc], bfrag, acc, 0, 0, 0);
    }
#pragma unroll
    for (int r = 0; r < 4; ++r) {
      int row = row0 + lq * 4 + r;
      if (row < nrows)
        hs[(size_t)row * HD + nt * 16 + lm] = bf16_rne(acc[r] * dv[r]);
    }
  }
}

// ---------------- gather (conv1): h1b = bf16(relu(dinv*(sum+self)+b)) ----------------
// One wave per node. lane = sub*16 + fl; sub = edge slot (4 edges/iter),
// fl = 16B feature slice (8 features). Rows loaded as dwordx4, x2 unrolled.
__global__ __launch_bounds__(256) void k_gather1(const uint4* __restrict__ hs4,
                                                 const float* __restrict__ dinv,
                                                 const int* __restrict__ rowptr,
                                                 const int* __restrict__ col,
                                                 const float* __restrict__ bias,
                                                 uint4* __restrict__ outp, int n) {
  int node = blockIdx.x * 4 + (threadIdx.x >> 6);
  int lane = threadIdx.x & 63;
  if (node >= n) return;
  const int sub = lane >> 4;
  const int fl = lane & 15;
  int beg = rowptr[node], end = rowptr[node + 1];

  float ax[8] = {0.f, 0.f, 0.f, 0.f, 0.f, 0.f, 0.f, 0.f};
  if (sub == 0) acc_row(ax, hs4[(size_t)node * 16 + fl]);  // self term, counted once

  int e = beg + sub;
  for (; e + 4 < end; e += 8) {
    int s0 = col[e];
    int s1 = col[e + 4];
    uint4 u0 = hs4[(size_t)s0 * 16 + fl];
    uint4 u1 = hs4[(size_t)s1 * 16 + fl];
    acc_row(ax, u0);
    acc_row(ax, u1);
  }
  if (e < end) acc_row(ax, hs4[(size_t)col[e] * 16 + fl]);

  // combine the 4 edge slots
#pragma unroll
  for (int i = 0; i < 8; ++i) {
    ax[i] += __shfl_xor(ax[i], 16);
    ax[i] += __shfl_xor(ax[i], 32);
  }

  if (sub == 0) {
    float di = dinv[node];
    float4 b0 = ((const float4*)bias)[fl * 2];
    float4 b1 = ((const float4*)bias)[fl * 2 + 1];
    uint4 o;
    o.x = pack_bf16x2(fmaxf(ax[0] * di + b0.x, 0.f), fmaxf(ax[1] * di + b0.y, 0.f));
    o.y = pack_bf16x2(fmaxf(ax[2] * di + b0.z, 0.f), fmaxf(ax[3] * di + b0.w, 0.f));
    o.z = pack_bf16x2(fmaxf(ax[4] * di + b1.x, 0.f), fmaxf(ax[5] * di + b1.y, 0.f));
    o.w = pack_bf16x2(fmaxf(ax[6] * di + b1.z, 0.f), fmaxf(ax[7] * di + b1.w, 0.f));
    outp[(size_t)node * 16 + fl] = o;
  }
}

// ---------------- gather (conv2) fused with scoring ----------------
__global__ __launch_bounds__(256) void k_gather_score(const uint4* __restrict__ hs4,
                                                      const float* __restrict__ dinv,
                                                      const int* __restrict__ rowptr,
                                                      const int* __restrict__ col,
                                                      const float* __restrict__ bias,
                                                      const float* __restrict__ Wl,
                                                      float* __restrict__ sv, int n) {
  int node = blockIdx.x * 4 + (threadIdx.x >> 6);
  int lane = threadIdx.x & 63;
  if (node >= n) return;
  const int sub = lane >> 4;
  const int fl = lane & 15;
  int beg = rowptr[node], end = rowptr[node + 1];

  float ax[8] = {0.f, 0.f, 0.f, 0.f, 0.f, 0.f, 0.f, 0.f};
  if (sub == 0) acc_row(ax, hs4[(size_t)node * 16 + fl]);

  int e = beg + sub;
  for (; e + 4 < end; e += 8) {
    int s0 = col[e];
    int s1 = col[e + 4];
    uint4 u0 = hs4[(size_t)s0 * 16 + fl];
    uint4 u1 = hs4[(size_t)s1 * 16 + fl];
    acc_row(ax, u0);
    acc_row(ax, u1);
  }
  if (e < end) acc_row(ax, hs4[(size_t)col[e] * 16 + fl]);

#pragma unroll
  for (int i = 0; i < 8; ++i) {
    ax[i] += __shfl_xor(ax[i], 16);
    ax[i] += __shfl_xor(ax[i], 32);
  }

  // per-lane partial dot over 8 features (all subs hold identical sums;
  // only sub 0's reduction result is used)
  float di = dinv[node];
  float4 b0 = ((const float4*)bias)[fl * 2];
  float4 b1 = ((const float4*)bias)[fl * 2 + 1];
  float h[8];
  h[0] = ax[0] * di + b0.x; h[1] = ax[1] * di + b0.y;
  h[2] = ax[2] * di + b0.z; h[3] = ax[3] * di + b0.w;
  h[4] = ax[4] * di + b1.x; h[5] = ax[5] * di + b1.y;
  h[6] = ax[6] * di + b1.z; h[7] = ax[7] * di + b1.w;
  float4 wa0 = ((const float4*)Wl)[fl * 2];
  float4 wa1 = ((const float4*)Wl)[fl * 2 + 1];
  float4 wb0 = ((const float4*)Wl)[32 + fl * 2];
  float4 wb1 = ((const float4*)Wl)[32 + fl * 2 + 1];
  float p1 = h[0] * wa0.x + h[1] * wa0.y + h[2] * wa0.z + h[3] * wa0.w +
             h[4] * wa1.x + h[5] * wa1.y + h[6] * wa1.z + h[7] * wa1.w;
  float p2 = h[0] * wb0.x + h[1] * wb0.y + h[2] * wb0.z + h[3] * wb0.w +
             h[4] * wb1.x + h[5] * wb1.y + h[6] * wb1.z + h[7] * wb1.w;
  // reduce over fl 0..15 (valid at fl==0 within each sub)
#pragma unroll
  for (int o = 8; o > 0; o >>= 1) {
    p1 += __shfl_down(p1, o);
    p2 += __shfl_down(p2, o);
  }
  if (lane == 0) {
    sv[node * 2] = p1;
    sv[node * 2 + 1] = p2;
  }
}

// ---------------- pair outputs ----------------
__global__ void k_pairs(const float* __restrict__ s, const int* __restrict__ I,
                        const int* __restrict__ J, const float* __restrict__ blin,
                        float* __restrict__ out, int np) {
  int p = blockIdx.x * 256 + threadIdx.x;
  if (p < np) {
    float v = s[2 * I[p]] + s[2 * J[p] + 1] + blin[0];
    out[p] = 1.f / (1.f + __expf(-v));
  }
}

extern "C" void kernel_launch(void* const* d_in, const int* in_sizes, int n_in,
                              void* d_out, int out_size, void* d_ws, size_t ws_size,
                              hipStream_t stream) {
  const float* x     = (const float*)d_in[0];
  const int*   eidx  = (const int*)d_in[1];
  const int*   Iidx  = (const int*)d_in[2];
  const int*   Jidx  = (const int*)d_in[3];
  const float* W1    = (const float*)d_in[4];
  const float* b1    = (const float*)d_in[5];
  const float* W2    = (const float*)d_in[6];
  const float* b2    = (const float*)d_in[7];
  const float* Wlin  = (const float*)d_in[8];
  const float* blin  = (const float*)d_in[9];
  const int* src = eidx;
  const int* dst = eidx + NE;

  // workspace layout (all offsets 16B-aligned)
  float* ws   = (float*)d_ws;
  float* dinv = ws;                                   // 100000
  float* sv   = dinv + 100000;                        // 200000
  unsigned int* hs  = (unsigned int*)(sv + 200000);   // NN*64 (bf16x2)
  unsigned int* h1b = hs + (size_t)NN * 64;           // NN*64 (bf16x2, relu'd)
  unsigned short* wt1 = (unsigned short*)(h1b + (size_t)NN * 64);  // 16384 bf16
  unsigned short* wt2 = wt1 + 16384;                  // 16384 bf16
  int* cnt    = (int*)(wt2 + 16384);                  // NPAD
  int* rowptr = cnt + NPAD;                           // NN+1 (pad 100004)
  int* col    = rowptr + 100004;                      // NE
  int* bsum   = col + NE;                             // 128
  int* gcursor= bsum + 128;                           // 784
  uint2* binned = (uint2*)(gcursor + 784);            // NE x 8B

  float* out = (float*)d_out;

  // ---- CSR build ----
  k_zero_int<<<(NPAD + 255) / 256, 256, 0, stream>>>(cnt, NPAD);
  k_count<<<(NE + 255) / 256, 256, 0, stream>>>(dst, cnt, NE);
  k_dinv<<<(NN + 255) / 256, 256, 0, stream>>>(cnt, dinv, NN);
  k_scan1<<<NBLK, 256, 0, stream>>>(cnt, rowptr, bsum);
  k_scan2<<<1, 128, 0, stream>>>(bsum);
  k_scan3<<<NBLK, 256, 0, stream>>>(rowptr, bsum);
  k_initgcur<<<(NB + 255) / 256, 256, 0, stream>>>(rowptr, gcursor);
  k_binA<<<(NE + CHUNK - 1) / CHUNK, 256, 0, stream>>>(src, dst, gcursor, binned, NE);
  k_binB<<<NB, 256, 0, stream>>>(binned, rowptr, col);

  // ---- weight prep ----
  k_wconv<<<64, 256, 0, stream>>>(W1, wt1);
  k_wconv<<<64, 256, 0, stream>>>(W2, wt2);

  const int gemm_grid = (NN + 63) / 64;
  const int gth_grid = (NN + 3) / 4;

  // conv1: hs = bf16(dinv*(x@W1)); h1b = bf16(relu(gather))
  k_gemm_mfma<false><<<gemm_grid, 256, 0, stream>>>(x, wt1, dinv, (unsigned short*)hs, NN);
  k_gather1<<<gth_grid, 256, 0, stream>>>((const uint4*)hs, dinv, rowptr, col, b1, (uint4*)h1b, NN);

  // conv2: hs = bf16(dinv*(h1b@W2)); score fused into gather
  k_gemm_mfma<true><<<gemm_grid, 256, 0, stream>>>(h1b, wt2, dinv, (unsigned short*)hs, NN);
  k_gather_score<<<gth_grid, 256, 0, stream>>>((const uint4*)hs, dinv, rowptr, col, b2, Wlin, sv, NN);

  // pair outputs
  k_pairs<<<(NP + 255) / 256, 256, 0, stream>>>(sv, Iidx, Jidx, blin, out, NP);
}

// Round 8
// 360.538 us; speedup vs baseline: 4.6750x; 1.1790x over previous
//
#include <hip/hip_runtime.h>
#include <hip/hip_bf16.h>
#include <math.h>

#define NN 100000
#define NE 1600000
#define NP 500000
#define HD 128
#define NPB 128                    // nodes per bucket (pow2)
#define NB 782                     // ceil(NN/NPB)
#define CHUNK 4096                 // edges per binning workgroup
#define NWG 391                    // ceil(NE/CHUNK)

typedef __attribute__((ext_vector_type(8))) short short8;   // 8 bf16 = 4 VGPRs
typedef __attribute__((ext_vector_type(4))) float f32x4;

// ---- bf16 helpers ----
__device__ __forceinline__ float bf_lo(unsigned int u) { return __uint_as_float(u << 16); }
__device__ __forceinline__ float bf_hi(unsigned int u) { return __uint_as_float(u & 0xffff0000u); }
__device__ __forceinline__ unsigned short bf16_rne(float f) {
  unsigned int u = __float_as_uint(f);
  u = (u + 0x7fffu + ((u >> 16) & 1u)) >> 16;
  return (unsigned short)u;
}
__device__ __forceinline__ unsigned int pack_bf16x2(float a, float b) {
  return (unsigned int)bf16_rne(a) | ((unsigned int)bf16_rne(b) << 16);
}
__device__ __forceinline__ void acc_row(float* ax, uint4 u) {
  ax[0] += bf_lo(u.x); ax[1] += bf_hi(u.x);
  ax[2] += bf_lo(u.y); ax[3] += bf_hi(u.y);
  ax[4] += bf_lo(u.z); ax[5] += bf_hi(u.z);
  ax[6] += bf_lo(u.w); ax[7] += bf_hi(u.w);
}

// ---------------- bucket histogram: bh[wg][b] (coalesced, no global atomics) ----------------
__global__ __launch_bounds__(256) void k_bhist(const int* __restrict__ dst,
                                               int* __restrict__ bh, int ne) {
  __shared__ int hist[NB];
  const int t = threadIdx.x;
  const int e0 = blockIdx.x * CHUNK;
  for (int i = t; i < NB; i += 256) hist[i] = 0;
  __syncthreads();
#pragma unroll
  for (int k = 0; k < CHUNK / 256; ++k) {
    int e = e0 + k * 256 + t;
    if (e < ne) atomicAdd(&hist[dst[e] >> 7], 1);
  }
  __syncthreads();
  for (int i = t; i < NB; i += 256) bh[blockIdx.x * NB + i] = hist[i];
}

// ---------------- column-sum: bcnt[b] = sum_wg bh[wg][b] ----------------
__global__ __launch_bounds__(64) void k_breduce(const int* __restrict__ bh,
                                                int* __restrict__ bcnt) {
  const int b = blockIdx.x;
  const int t = threadIdx.x;
  int s = 0;
  for (int w = t; w < NWG; w += 64) s += bh[w * NB + b];
#pragma unroll
  for (int o = 32; o > 0; o >>= 1) s += __shfl_down(s, o);
  if (t == 0) bcnt[b] = s;
}

// ---------------- exclusive scan of 782 bucket counts (1 block) ----------------
__global__ __launch_bounds__(256) void k_bscan(const int* __restrict__ bcnt,
                                               int* __restrict__ bbase,
                                               int* __restrict__ gcursor) {
  __shared__ int sh[256];
  const int t = threadIdx.x;
  const int base = t * 4;
  int v0 = (base + 0 < NB) ? bcnt[base + 0] : 0;
  int v1 = (base + 1 < NB) ? bcnt[base + 1] : 0;
  int v2 = (base + 2 < NB) ? bcnt[base + 2] : 0;
  int v3 = (base + 3 < NB) ? bcnt[base + 3] : 0;
  int s0 = v0, s1 = s0 + v1, s2 = s1 + v2, s3 = s2 + v3;
  sh[t] = s3;
  __syncthreads();
  int run = s3;
#pragma unroll
  for (int o = 1; o < 256; o <<= 1) {
    int add = (t >= o) ? sh[t - o] : 0;
    __syncthreads();
    sh[t] += add;
    __syncthreads();
  }
  int exc = sh[t] - run;
  int p[4] = {exc, exc + s0, exc + s1, exc + s2};
#pragma unroll
  for (int i = 0; i < 4; ++i) {
    if (base + i < NB) {
      bbase[base + i] = p[i];
      gcursor[base + i] = p[i];
    }
  }
  if (t == 0) bbase[NB] = NE;
}

// ---- binA: bin edges into per-bucket contiguous regions (8B entries) ----
__global__ __launch_bounds__(256) void k_binA(const int* __restrict__ src,
                                              const int* __restrict__ dst,
                                              int* __restrict__ gcursor,
                                              uint2* __restrict__ binned, int ne) {
  __shared__ int hist[NB];
  __shared__ int base[NB];
  const int t = threadIdx.x;
  const int e0 = blockIdx.x * CHUNK;

  for (int i = t; i < NB; i += 256) hist[i] = 0;
  __syncthreads();

#pragma unroll
  for (int k = 0; k < CHUNK / 256; ++k) {
    int e = e0 + k * 256 + t;
    if (e < ne) atomicAdd(&hist[dst[e] >> 7], 1);
  }
  __syncthreads();

  for (int i = t; i < NB; i += 256) {
    int c = hist[i];
    base[i] = c ? atomicAdd(&gcursor[i], c) : 0;
    hist[i] = 0;
  }
  __syncthreads();

#pragma unroll
  for (int k = 0; k < CHUNK / 256; ++k) {
    int e = e0 + k * 256 + t;
    if (e < ne) {
      int d = dst[e];
      int b = d >> 7;
      int pos = base[b] + atomicAdd(&hist[b], 1);
      binned[pos] = make_uint2((unsigned int)src[e], (unsigned int)d);
    }
  }
}

// ---- binB: per-node count (LDS) -> rowptr + dinv, then exact CSR placement ----
__global__ __launch_bounds__(256) void k_binB(const uint2* __restrict__ binned,
                                              const int* __restrict__ bbase,
                                              int* __restrict__ rowptr,
                                              int* __restrict__ col,
                                              float* __restrict__ dinv) {
  __shared__ int hcnt[NPB];
  __shared__ int sc[NPB];
  __shared__ int lcur[NPB];
  const int b = blockIdx.x;
  const int t = threadIdx.x;
  const int node0 = b * NPB;
  const int node1 = (node0 + NPB > NN) ? NN : node0 + NPB;
  const int nnode = node1 - node0;
  if (t < NPB) hcnt[t] = 0;
  __syncthreads();

  const int gbase = bbase[b];
  const int gend = bbase[b + 1];
  for (int i = gbase + t; i < gend; i += 256)
    atomicAdd(&hcnt[binned[i].y - node0], 1);
  __syncthreads();

  int v = (t < NPB) ? hcnt[t] : 0;
  if (t < NPB) sc[t] = v;
  __syncthreads();
#pragma unroll
  for (int o = 1; o < NPB; o <<= 1) {
    int add = (t < NPB && t >= o) ? sc[t - o] : 0;
    __syncthreads();
    if (t < NPB) sc[t] += add;
    __syncthreads();
  }
  if (t < nnode) {
    int rp = gbase + sc[t] - v;   // exclusive
    rowptr[node0 + t] = rp;
    lcur[t] = rp;
    dinv[node0 + t] = rsqrtf((float)v + 1.0f);
  }
  if (b == NB - 1 && t == 0) rowptr[NN] = NE;
  __syncthreads();

  for (int i = gbase + t; i < gend; i += 256) {
    uint2 p = binned[i];
    int pos = atomicAdd(&lcur[p.y - node0], 1);
    col[pos] = (int)p.x;
  }
}

// ---------------- W transpose+cast: Wt[n][k] = bf16(W[k][n]) ----------------
__global__ void k_wconv(const float* __restrict__ W, unsigned short* __restrict__ Wt) {
  int t = blockIdx.x * 256 + threadIdx.x;  // 16384
  int n = t >> 7, k = t & 127;
  Wt[t] = bf16_rne(W[k * HD + n]);
}

// ---------------- MFMA GEMM: hs[n][c] = bf16( dinv[n] * (X @ W)[n][c] ) ----------------
template <bool SRC_BF16>
__global__ __launch_bounds__(256) void k_gemm_mfma(const void* __restrict__ Xsrc,
                                                   const unsigned short* __restrict__ Wt,
                                                   const float* __restrict__ dinv,
                                                   unsigned short* __restrict__ hs,
                                                   int nrows) {
  const int wave = threadIdx.x >> 6;
  const int lane = threadIdx.x & 63;
  const int row0 = blockIdx.x * 64 + wave * 16;
  if (row0 >= nrows) return;
  const int lm = lane & 15;   // A-row / C-col
  const int lq = lane >> 4;   // quad

  int arow = row0 + lm;
  int arowc = arow < nrows ? arow : nrows - 1;  // clamp (stores are guarded)

  short8 afrag[4];
  if (SRC_BF16) {
    const unsigned short* X = (const unsigned short*)Xsrc;
#pragma unroll
    for (int kc = 0; kc < 4; ++kc) {
      int k0 = kc * 32 + lq * 8;
      afrag[kc] = *(const short8*)(X + (size_t)arowc * HD + k0);
    }
  } else {
    const float* X = (const float*)Xsrc;
#pragma unroll
    for (int kc = 0; kc < 4; ++kc) {
      int k0 = kc * 32 + lq * 8;
      const float4* p = (const float4*)(X + (size_t)arowc * HD + k0);
      float4 f0 = p[0], f1 = p[1];
      short8 a;
      a[0] = (short)bf16_rne(f0.x); a[1] = (short)bf16_rne(f0.y);
      a[2] = (short)bf16_rne(f0.z); a[3] = (short)bf16_rne(f0.w);
      a[4] = (short)bf16_rne(f1.x); a[5] = (short)bf16_rne(f1.y);
      a[6] = (short)bf16_rne(f1.z); a[7] = (short)bf16_rne(f1.w);
      afrag[kc] = a;
    }
  }

  float dv[4];
#pragma unroll
  for (int r = 0; r < 4; ++r) {
    int row = row0 + lq * 4 + r;
    dv[r] = dinv[row < nrows ? row : 0];
  }

#pragma unroll
  for (int nt = 0; nt < 8; ++nt) {
    f32x4 acc = {0.f, 0.f, 0.f, 0.f};
    const unsigned short* Wb = Wt + (size_t)(nt * 16 + lm) * HD + lq * 8;
#pragma unroll
    for (int kc = 0; kc < 4; ++kc) {
      short8 bfrag = *(const short8*)(Wb + kc * 32);
      acc = __builtin_amdgcn_mfma_f32_16x16x32_bf16(afrag[kc], bfrag, acc, 0, 0, 0);
    }
#pragma unroll
    for (int r = 0; r < 4; ++r) {
      int row = row0 + lq * 4 + r;
      if (row < nrows)
        hs[(size_t)row * HD + nt * 16 + lm] = bf16_rne(acc[r] * dv[r]);
    }
  }
}

// ---------------- gather (conv1): h1b = bf16(relu(dinv*(sum+self)+b)) ----------------
// One wave per node. lane = sub*16 + fl; sub = edge slot, fl = 16B feature slice.
__global__ __launch_bounds__(256) void k_gather1(const uint4* __restrict__ hs4,
                                                 const float* __restrict__ dinv,
                                                 const int* __restrict__ rowptr,
                                                 const int* __restrict__ col,
                                                 const float* __restrict__ bias,
                                                 uint4* __restrict__ outp, int n) {
  int node = blockIdx.x * 4 + (threadIdx.x >> 6);
  int lane = threadIdx.x & 63;
  if (node >= n) return;
  const int sub = lane >> 4;
  const int fl = lane & 15;
  int beg = rowptr[node], end = rowptr[node + 1];

  float ax[8] = {0.f, 0.f, 0.f, 0.f, 0.f, 0.f, 0.f, 0.f};
  if (sub == 0) acc_row(ax, hs4[(size_t)node * 16 + fl]);  // self term

  int e = beg + sub;
  for (; e + 4 < end; e += 8) {
    int s0 = col[e];
    int s1 = col[e + 4];
    uint4 u0 = hs4[(size_t)s0 * 16 + fl];
    uint4 u1 = hs4[(size_t)s1 * 16 + fl];
    acc_row(ax, u0);
    acc_row(ax, u1);
  }
  if (e < end) acc_row(ax, hs4[(size_t)col[e] * 16 + fl]);

#pragma unroll
  for (int i = 0; i < 8; ++i) {
    ax[i] += __shfl_xor(ax[i], 16);
    ax[i] += __shfl_xor(ax[i], 32);
  }

  if (sub == 0) {
    float di = dinv[node];
    float4 b0 = ((const float4*)bias)[fl * 2];
    float4 b1 = ((const float4*)bias)[fl * 2 + 1];
    uint4 o;
    o.x = pack_bf16x2(fmaxf(ax[0] * di + b0.x, 0.f), fmaxf(ax[1] * di + b0.y, 0.f));
    o.y = pack_bf16x2(fmaxf(ax[2] * di + b0.z, 0.f), fmaxf(ax[3] * di + b0.w, 0.f));
    o.z = pack_bf16x2(fmaxf(ax[4] * di + b1.x, 0.f), fmaxf(ax[5] * di + b1.y, 0.f));
    o.w = pack_bf16x2(fmaxf(ax[6] * di + b1.z, 0.f), fmaxf(ax[7] * di + b1.w, 0.f));
    outp[(size_t)node * 16 + fl] = o;
  }
}

// ---------------- gather (conv2) fused with scoring ----------------
__global__ __launch_bounds__(256) void k_gather_score(const uint4* __restrict__ hs4,
                                                      const float* __restrict__ dinv,
                                                      const int* __restrict__ rowptr,
                                                      const int* __restrict__ col,
                                                      const float* __restrict__ bias,
                                                      const float* __restrict__ Wl,
                                                      float* __restrict__ sv, int n) {
  int node = blockIdx.x * 4 + (threadIdx.x >> 6);
  int lane = threadIdx.x & 63;
  if (node >= n) return;
  const int sub = lane >> 4;
  const int fl = lane & 15;
  int beg = rowptr[node], end = rowptr[node + 1];

  float ax[8] = {0.f, 0.f, 0.f, 0.f, 0.f, 0.f, 0.f, 0.f};
  if (sub == 0) acc_row(ax, hs4[(size_t)node * 16 + fl]);

  int e = beg + sub;
  for (; e + 4 < end; e += 8) {
    int s0 = col[e];
    int s1 = col[e + 4];
    uint4 u0 = hs4[(size_t)s0 * 16 + fl];
    uint4 u1 = hs4[(size_t)s1 * 16 + fl];
    acc_row(ax, u0);
    acc_row(ax, u1);
  }
  if (e < end) acc_row(ax, hs4[(size_t)col[e] * 16 + fl]);

#pragma unroll
  for (int i = 0; i < 8; ++i) {
    ax[i] += __shfl_xor(ax[i], 16);
    ax[i] += __shfl_xor(ax[i], 32);
  }

  float di = dinv[node];
  float4 b0 = ((const float4*)bias)[fl * 2];
  float4 b1 = ((const float4*)bias)[fl * 2 + 1];
  float h[8];
  h[0] = ax[0] * di + b0.x; h[1] = ax[1] * di + b0.y;
  h[2] = ax[2] * di + b0.z; h[3] = ax[3] * di + b0.w;
  h[4] = ax[4] * di + b1.x; h[5] = ax[5] * di + b1.y;
  h[6] = ax[6] * di + b1.z; h[7] = ax[7] * di + b1.w;
  float4 wa0 = ((const float4*)Wl)[fl * 2];
  float4 wa1 = ((const float4*)Wl)[fl * 2 + 1];
  float4 wb0 = ((const float4*)Wl)[32 + fl * 2];
  float4 wb1 = ((const float4*)Wl)[32 + fl * 2 + 1];
  float p1 = h[0] * wa0.x + h[1] * wa0.y + h[2] * wa0.z + h[3] * wa0.w +
             h[4] * wa1.x + h[5] * wa1.y + h[6] * wa1.z + h[7] * wa1.w;
  float p2 = h[0] * wb0.x + h[1] * wb0.y + h[2] * wb0.z + h[3] * wb0.w +
             h[4] * wb1.x + h[5] * wb1.y + h[6] * wb1.z + h[7] * wb1.w;
#pragma unroll
  for (int o = 8; o > 0; o >>= 1) {
    p1 += __shfl_down(p1, o);
    p2 += __shfl_down(p2, o);
  }
  if (lane == 0) {
    sv[node * 2] = p1;
    sv[node * 2 + 1] = p2;
  }
}

// ---------------- pair outputs ----------------
__global__ void k_pairs(const float* __restrict__ s, const int* __restrict__ I,
                        const int* __restrict__ J, const float* __restrict__ blin,
                        float* __restrict__ out, int np) {
  int p = blockIdx.x * 256 + threadIdx.x;
  if (p < np) {
    float v = s[2 * I[p]] + s[2 * J[p] + 1] + blin[0];
    out[p] = 1.f / (1.f + __expf(-v));
  }
}

extern "C" void kernel_launch(void* const* d_in, const int* in_sizes, int n_in,
                              void* d_out, int out_size, void* d_ws, size_t ws_size,
                              hipStream_t stream) {
  const float* x     = (const float*)d_in[0];
  const int*   eidx  = (const int*)d_in[1];
  const int*   Iidx  = (const int*)d_in[2];
  const int*   Jidx  = (const int*)d_in[3];
  const float* W1    = (const float*)d_in[4];
  const float* b1    = (const float*)d_in[5];
  const float* W2    = (const float*)d_in[6];
  const float* b2    = (const float*)d_in[7];
  const float* Wlin  = (const float*)d_in[8];
  const float* blin  = (const float*)d_in[9];
  const int* src = eidx;
  const int* dst = eidx + NE;

  // workspace layout (int offsets; binned offset is even -> 8B aligned)
  float* ws   = (float*)d_ws;
  float* dinv = ws;                                   // 100000
  float* sv   = dinv + 100000;                        // 200000
  unsigned int* hs  = (unsigned int*)(sv + 200000);   // NN*64 (bf16x2)
  unsigned int* h1b = hs + (size_t)NN * 64;           // NN*64 (bf16x2, relu'd)
  unsigned short* wt1 = (unsigned short*)(h1b + (size_t)NN * 64);  // 16384 bf16
  unsigned short* wt2 = wt1 + 16384;                  // 16384 bf16
  int* rowptr = (int*)(wt2 + 16384);                  // NN+1 (pad 100004)
  int* col    = rowptr + 100004;                      // NE
  int* gcursor= col + NE;                             // NB (pad 784)
  int* bcnt   = gcursor + 784;                        // NB (pad 784)
  int* bbase  = bcnt + 784;                           // NB+1 (pad 784)
  int* bh     = bbase + 784;                          // NWG*NB (pad 305764)
  uint2* binned = (uint2*)(bh + 305764);              // NE x 8B

  float* out = (float*)d_out;

  // ---- CSR build (no global per-node atomics) ----
  k_bhist<<<NWG, 256, 0, stream>>>(dst, bh, NE);
  k_breduce<<<NB, 64, 0, stream>>>(bh, bcnt);
  k_bscan<<<1, 256, 0, stream>>>(bcnt, bbase, gcursor);
  k_binA<<<NWG, 256, 0, stream>>>(src, dst, gcursor, binned, NE);
  k_binB<<<NB, 256, 0, stream>>>(binned, bbase, rowptr, col, dinv);

  // ---- weight prep ----
  k_wconv<<<64, 256, 0, stream>>>(W1, wt1);
  k_wconv<<<64, 256, 0, stream>>>(W2, wt2);

  const int gemm_grid = (NN + 63) / 64;
  const int gth_grid = (NN + 3) / 4;

  // conv1: hs = bf16(dinv*(x@W1)); h1b = bf16(relu(gather))
  k_gemm_mfma<false><<<gemm_grid, 256, 0, stream>>>(x, wt1, dinv, (unsigned short*)hs, NN);
  k_gather1<<<gth_grid, 256, 0, stream>>>((const uint4*)hs, dinv, rowptr, col, b1, (uint4*)h1b, NN);

  // conv2: hs = bf16(dinv*(h1b@W2)); score fused into gather
  k_gemm_mfma<true><<<gemm_grid, 256, 0, stream>>>(h1b, wt2, dinv, (unsigned short*)hs, NN);
  k_gather_score<<<gth_grid, 256, 0, stream>>>((const uint4*)hs, dinv, rowptr, col, b2, Wlin, sv, NN);

  // pair outputs
  k_pairs<<<(NP + 255) / 256, 256, 0, stream>>>(sv, Iidx, Jidx, blin, out, NP);
}

// Round 9
// 301.083 us; speedup vs baseline: 5.5982x; 1.1975x over previous
//
#include <hip/hip_runtime.h>
#include <hip/hip_bf16.h>
#include <math.h>

#define NN 100000
#define NE 1600000
#define NP 500000
#define HD 128
#define NPB 128                    // nodes per bucket (pow2)
#define NB 782                     // ceil(NN/NPB)
#define CHUNK 4096                 // edges per binning workgroup
#define NWG 391                    // ceil(NE/CHUNK)

typedef __attribute__((ext_vector_type(8))) short short8;   // 8 bf16 = 4 VGPRs
typedef __attribute__((ext_vector_type(4))) float f32x4;

// ---- bf16 helpers ----
__device__ __forceinline__ float bf_lo(unsigned int u) { return __uint_as_float(u << 16); }
__device__ __forceinline__ float bf_hi(unsigned int u) { return __uint_as_float(u & 0xffff0000u); }
__device__ __forceinline__ unsigned short bf16_rne(float f) {
  unsigned int u = __float_as_uint(f);
  u = (u + 0x7fffu + ((u >> 16) & 1u)) >> 16;
  return (unsigned short)u;
}
__device__ __forceinline__ void acc_row(float* ax, uint4 u) {
  ax[0] += bf_lo(u.x); ax[1] += bf_hi(u.x);
  ax[2] += bf_lo(u.y); ax[3] += bf_hi(u.y);
  ax[4] += bf_lo(u.z); ax[5] += bf_hi(u.z);
  ax[6] += bf_lo(u.w); ax[7] += bf_hi(u.w);
}

// ---------------- bucket histogram: bh[wg][b] ----------------
__global__ __launch_bounds__(256) void k_bhist(const int* __restrict__ dst,
                                               int* __restrict__ bh, int ne) {
  __shared__ int hist[NB];
  const int t = threadIdx.x;
  const int e0 = blockIdx.x * CHUNK;
  for (int i = t; i < NB; i += 256) hist[i] = 0;
  __syncthreads();
#pragma unroll
  for (int k = 0; k < CHUNK / 256; ++k) {
    int e = e0 + k * 256 + t;
    if (e < ne) atomicAdd(&hist[dst[e] >> 7], 1);
  }
  __syncthreads();
  for (int i = t; i < NB; i += 256) bh[blockIdx.x * NB + i] = hist[i];
}

// ---------------- column-sum: bcnt[b] = sum_wg bh[wg][b] ----------------
__global__ __launch_bounds__(64) void k_breduce(const int* __restrict__ bh,
                                                int* __restrict__ bcnt) {
  const int b = blockIdx.x;
  const int t = threadIdx.x;
  int s = 0;
  for (int w = t; w < NWG; w += 64) s += bh[w * NB + b];
#pragma unroll
  for (int o = 32; o > 0; o >>= 1) s += __shfl_down(s, o);
  if (t == 0) bcnt[b] = s;
}

// ---------------- exclusive scan of NB bucket counts (1 block) ----------------
__global__ __launch_bounds__(256) void k_bscan(const int* __restrict__ bcnt,
                                               int* __restrict__ bbase,
                                               int* __restrict__ gcursor) {
  __shared__ int sh[256];
  const int t = threadIdx.x;
  const int base = t * 4;
  int v0 = (base + 0 < NB) ? bcnt[base + 0] : 0;
  int v1 = (base + 1 < NB) ? bcnt[base + 1] : 0;
  int v2 = (base + 2 < NB) ? bcnt[base + 2] : 0;
  int v3 = (base + 3 < NB) ? bcnt[base + 3] : 0;
  int s0 = v0, s1 = s0 + v1, s2 = s1 + v2, s3 = s2 + v3;
  sh[t] = s3;
  __syncthreads();
  int run = s3;
#pragma unroll
  for (int o = 1; o < 256; o <<= 1) {
    int add = (t >= o) ? sh[t - o] : 0;
    __syncthreads();
    sh[t] += add;
    __syncthreads();
  }
  int exc = sh[t] - run;
  int p[4] = {exc, exc + s0, exc + s1, exc + s2};
#pragma unroll
  for (int i = 0; i < 4; ++i) {
    if (base + i < NB) {
      bbase[base + i] = p[i];
      gcursor[base + i] = p[i];
    }
  }
  if (t == 0) bbase[NB] = NE;
}

// ---- binA: bin edges into per-bucket contiguous regions (8B entries) ----
__global__ __launch_bounds__(256) void k_binA(const int* __restrict__ src,
                                              const int* __restrict__ dst,
                                              int* __restrict__ gcursor,
                                              uint2* __restrict__ binned, int ne) {
  __shared__ int hist[NB];
  __shared__ int base[NB];
  const int t = threadIdx.x;
  const int e0 = blockIdx.x * CHUNK;

  for (int i = t; i < NB; i += 256) hist[i] = 0;
  __syncthreads();

#pragma unroll
  for (int k = 0; k < CHUNK / 256; ++k) {
    int e = e0 + k * 256 + t;
    if (e < ne) atomicAdd(&hist[dst[e] >> 7], 1);
  }
  __syncthreads();

  for (int i = t; i < NB; i += 256) {
    int c = hist[i];
    base[i] = c ? atomicAdd(&gcursor[i], c) : 0;
    hist[i] = 0;
  }
  __syncthreads();

#pragma unroll
  for (int k = 0; k < CHUNK / 256; ++k) {
    int e = e0 + k * 256 + t;
    if (e < ne) {
      int d = dst[e];
      int b = d >> 7;
      int pos = base[b] + atomicAdd(&hist[b], 1);
      binned[pos] = make_uint2((unsigned int)src[e], (unsigned int)d);
    }
  }
}

// ---- binB: per-node count (LDS) -> rowptr + dinv, then exact CSR placement ----
__global__ __launch_bounds__(256) void k_binB(const uint2* __restrict__ binned,
                                              const int* __restrict__ bbase,
                                              int* __restrict__ rowptr,
                                              int* __restrict__ col,
                                              float* __restrict__ dinv) {
  __shared__ int hcnt[NPB];
  __shared__ int sc[NPB];
  __shared__ int lcur[NPB];
  const int b = blockIdx.x;
  const int t = threadIdx.x;
  const int node0 = b * NPB;
  const int node1 = (node0 + NPB > NN) ? NN : node0 + NPB;
  const int nnode = node1 - node0;
  if (t < NPB) hcnt[t] = 0;
  __syncthreads();

  const int gbase = bbase[b];
  const int gend = bbase[b + 1];
  for (int i = gbase + t; i < gend; i += 256)
    atomicAdd(&hcnt[binned[i].y - node0], 1);
  __syncthreads();

  int v = (t < NPB) ? hcnt[t] : 0;
  if (t < NPB) sc[t] = v;
  __syncthreads();
#pragma unroll
  for (int o = 1; o < NPB; o <<= 1) {
    int add = (t < NPB && t >= o) ? sc[t - o] : 0;
    __syncthreads();
    if (t < NPB) sc[t] += add;
    __syncthreads();
  }
  if (t < nnode) {
    int rp = gbase + sc[t] - v;   // exclusive
    rowptr[node0 + t] = rp;
    lcur[t] = rp;
    dinv[node0 + t] = rsqrtf((float)v + 1.0f);
  }
  if (b == NB - 1 && t == 0) rowptr[NN] = NE;
  __syncthreads();

  for (int i = gbase + t; i < gend; i += 256) {
    uint2 p = binned[i];
    int pos = atomicAdd(&lcur[p.y - node0], 1);
    col[pos] = (int)p.x;
  }
}

// ---------------- W transpose+cast: Wt[n][k] = bf16(W[k][n]) ----------------
__global__ void k_wconv(const float* __restrict__ W, unsigned short* __restrict__ Wt) {
  int t = blockIdx.x * 256 + threadIdx.x;  // 16384
  int n = t >> 7, k = t & 127;
  Wt[t] = bf16_rne(W[k * HD + n]);
}

// ---------------- u-vector prep: u1 = W2@Wl[:128], u2 = W2@Wl[128:], c1/c2 = b2.Wl ----------------
// uv layout: [0..127]=u1, [128..255]=u2, [256]=c1, [257]=c2
__global__ __launch_bounds__(256) void k_uvec(const float* __restrict__ W2,
                                              const float* __restrict__ Wl,
                                              const float* __restrict__ b2,
                                              float* __restrict__ uv) {
  __shared__ float sh[256];
  const int t = threadIdx.x;
  const int half = t >> 7;
  const int k = t & 127;
  const float* wl = Wl + half * 128;
  float s = 0.f;
  for (int c = 0; c < 128; ++c) s += W2[k * HD + c] * wl[c];
  uv[half * 128 + k] = s;

  sh[t] = b2[k] * Wl[half * 128 + k];
  __syncthreads();
  for (int o = 64; o > 0; o >>= 1) {
    if ((t & 127) < o) sh[t] += sh[t + o];
    __syncthreads();
  }
  if (t == 0) uv[256] = sh[0];
  if (t == 128) uv[257] = sh[128];
}

// ---------------- MFMA GEMM: hs[n][c] = bf16( dinv[n] * (X @ W)[n][c] ) ----------------
__global__ __launch_bounds__(256) void k_gemm_mfma(const float* __restrict__ X,
                                                   const unsigned short* __restrict__ Wt,
                                                   const float* __restrict__ dinv,
                                                   unsigned short* __restrict__ hs,
                                                   int nrows) {
  const int wave = threadIdx.x >> 6;
  const int lane = threadIdx.x & 63;
  const int row0 = blockIdx.x * 64 + wave * 16;
  if (row0 >= nrows) return;
  const int lm = lane & 15;   // A-row / C-col
  const int lq = lane >> 4;   // quad

  int arow = row0 + lm;
  int arowc = arow < nrows ? arow : nrows - 1;  // clamp (stores are guarded)

  short8 afrag[4];
#pragma unroll
  for (int kc = 0; kc < 4; ++kc) {
    int k0 = kc * 32 + lq * 8;
    const float4* p = (const float4*)(X + (size_t)arowc * HD + k0);
    float4 f0 = p[0], f1 = p[1];
    short8 a;
    a[0] = (short)bf16_rne(f0.x); a[1] = (short)bf16_rne(f0.y);
    a[2] = (short)bf16_rne(f0.z); a[3] = (short)bf16_rne(f0.w);
    a[4] = (short)bf16_rne(f1.x); a[5] = (short)bf16_rne(f1.y);
    a[6] = (short)bf16_rne(f1.z); a[7] = (short)bf16_rne(f1.w);
    afrag[kc] = a;
  }

  float dv[4];
#pragma unroll
  for (int r = 0; r < 4; ++r) {
    int row = row0 + lq * 4 + r;
    dv[r] = dinv[row < nrows ? row : 0];
  }

#pragma unroll
  for (int nt = 0; nt < 8; ++nt) {
    f32x4 acc = {0.f, 0.f, 0.f, 0.f};
    const unsigned short* Wb = Wt + (size_t)(nt * 16 + lm) * HD + lq * 8;
#pragma unroll
    for (int kc = 0; kc < 4; ++kc) {
      short8 bfrag = *(const short8*)(Wb + kc * 32);
      acc = __builtin_amdgcn_mfma_f32_16x16x32_bf16(afrag[kc], bfrag, acc, 0, 0, 0);
    }
#pragma unroll
    for (int r = 0; r < 4; ++r) {
      int row = row0 + lq * 4 + r;
      if (row < nrows)
        hs[(size_t)row * HD + nt * 16 + lm] = bf16_rne(acc[r] * dv[r]);
    }
  }
}

// ---------------- gather1 + relu + fused score-projection ----------------
// One wave per node. lane = sub*16 + fl; sub = edge slot, fl = 16B feature slice.
// h = relu(dinv*(sum_nbr hs + hs_self) + b1)  [fp32, in registers]
// q[node] = ( dinv*(h.u1), dinv*(h.u2) )   [the only output]
__global__ __launch_bounds__(256) void k_gather1q(const uint4* __restrict__ hs4,
                                                  const float* __restrict__ dinv,
                                                  const int* __restrict__ rowptr,
                                                  const int* __restrict__ col,
                                                  const float* __restrict__ bias,
                                                  const float* __restrict__ uv,
                                                  float2* __restrict__ q, int n) {
  int node = blockIdx.x * 4 + (threadIdx.x >> 6);
  int lane = threadIdx.x & 63;
  if (node >= n) return;
  const int sub = lane >> 4;
  const int fl = lane & 15;
  int beg = rowptr[node], end = rowptr[node + 1];

  float ax[8] = {0.f, 0.f, 0.f, 0.f, 0.f, 0.f, 0.f, 0.f};
  if (sub == 0) acc_row(ax, hs4[(size_t)node * 16 + fl]);  // self term

  int e = beg + sub;
  for (; e + 12 < end; e += 16) {
    int s0 = col[e], s1 = col[e + 4], s2 = col[e + 8], s3 = col[e + 12];
    uint4 u0 = hs4[(size_t)s0 * 16 + fl];
    uint4 u1 = hs4[(size_t)s1 * 16 + fl];
    uint4 u2 = hs4[(size_t)s2 * 16 + fl];
    uint4 u3 = hs4[(size_t)s3 * 16 + fl];
    acc_row(ax, u0); acc_row(ax, u1); acc_row(ax, u2); acc_row(ax, u3);
  }
  for (; e < end; e += 4) acc_row(ax, hs4[(size_t)col[e] * 16 + fl]);

  // combine the 4 edge slots (all lanes end with full sums, replicated)
#pragma unroll
  for (int i = 0; i < 8; ++i) {
    ax[i] += __shfl_xor(ax[i], 16);
    ax[i] += __shfl_xor(ax[i], 32);
  }

  float di = dinv[node];
  float4 b0 = ((const float4*)bias)[fl * 2];
  float4 b1 = ((const float4*)bias)[fl * 2 + 1];
  float h[8];
  h[0] = fmaxf(ax[0] * di + b0.x, 0.f); h[1] = fmaxf(ax[1] * di + b0.y, 0.f);
  h[2] = fmaxf(ax[2] * di + b0.z, 0.f); h[3] = fmaxf(ax[3] * di + b0.w, 0.f);
  h[4] = fmaxf(ax[4] * di + b1.x, 0.f); h[5] = fmaxf(ax[5] * di + b1.y, 0.f);
  h[6] = fmaxf(ax[6] * di + b1.z, 0.f); h[7] = fmaxf(ax[7] * di + b1.w, 0.f);

  float4 ua0 = ((const float4*)uv)[fl * 2];
  float4 ua1 = ((const float4*)uv)[fl * 2 + 1];
  float4 ub0 = ((const float4*)uv)[32 + fl * 2];
  float4 ub1 = ((const float4*)uv)[32 + fl * 2 + 1];
  float p1 = h[0] * ua0.x + h[1] * ua0.y + h[2] * ua0.z + h[3] * ua0.w +
             h[4] * ua1.x + h[5] * ua1.y + h[6] * ua1.z + h[7] * ua1.w;
  float p2 = h[0] * ub0.x + h[1] * ub0.y + h[2] * ub0.z + h[3] * ub0.w +
             h[4] * ub1.x + h[5] * ub1.y + h[6] * ub1.z + h[7] * ub1.w;
#pragma unroll
  for (int o = 8; o > 0; o >>= 1) {
    p1 += __shfl_down(p1, o);
    p2 += __shfl_down(p2, o);
  }
  if (lane == 0) q[node] = make_float2(p1 * di, p2 * di);
}

// ---------------- q aggregation: sv[2n]/sv[2n+1] (scalar gather, q L2-resident) ----------------
__global__ __launch_bounds__(256) void k_qagg(const float2* __restrict__ q,
                                              const float* __restrict__ dinv,
                                              const int* __restrict__ rowptr,
                                              const int* __restrict__ col,
                                              const float* __restrict__ uv,
                                              float2* __restrict__ sv, int n) {
  int i = blockIdx.x * 256 + threadIdx.x;
  if (i >= n) return;
  int beg = rowptr[i], end = rowptr[i + 1];
  float2 a = q[i];
  float a1 = a.x, a2 = a.y;
  int e = beg;
  for (; e + 3 < end; e += 4) {
    float2 q0 = q[col[e]];
    float2 q1 = q[col[e + 1]];
    float2 q2 = q[col[e + 2]];
    float2 q3 = q[col[e + 3]];
    a1 += (q0.x + q1.x) + (q2.x + q3.x);
    a2 += (q0.y + q1.y) + (q2.y + q3.y);
  }
  for (; e < end; ++e) {
    float2 qq = q[col[e]];
    a1 += qq.x; a2 += qq.y;
  }
  float di = dinv[i];
  sv[i] = make_float2(a1 * di + uv[256], a2 * di + uv[257]);
}

// ---------------- pair outputs ----------------
__global__ void k_pairs(const float2* __restrict__ s, const int* __restrict__ I,
                        const int* __restrict__ J, const float* __restrict__ blin,
                        float* __restrict__ out, int np) {
  int p = blockIdx.x * 256 + threadIdx.x;
  if (p < np) {
    float v = s[I[p]].x + s[J[p]].y + blin[0];
    out[p] = 1.f / (1.f + __expf(-v));
  }
}

extern "C" void kernel_launch(void* const* d_in, const int* in_sizes, int n_in,
                              void* d_out, int out_size, void* d_ws, size_t ws_size,
                              hipStream_t stream) {
  const float* x     = (const float*)d_in[0];
  const int*   eidx  = (const int*)d_in[1];
  const int*   Iidx  = (const int*)d_in[2];
  const int*   Jidx  = (const int*)d_in[3];
  const float* W1    = (const float*)d_in[4];
  const float* b1    = (const float*)d_in[5];
  const float* W2    = (const float*)d_in[6];
  const float* b2    = (const float*)d_in[7];
  const float* Wlin  = (const float*)d_in[8];
  const float* blin  = (const float*)d_in[9];
  const int* src = eidx;
  const int* dst = eidx + NE;

  // workspace layout (int offsets; binned offset is even -> 8B aligned)
  float* ws   = (float*)d_ws;
  float* dinv = ws;                                   // 100000
  float* sv   = dinv + 100000;                        // 200000 (float2 per node)
  float* qbuf = sv + 200000;                          // 200000 (float2 per node)
  float* uv   = qbuf + 200000;                        // 260 -> pad 264
  unsigned int* hs  = (unsigned int*)(uv + 264);      // NN*64 (bf16x2)
  unsigned short* wt1 = (unsigned short*)(hs + (size_t)NN * 64);  // 16384 bf16
  int* rowptr = (int*)(wt1 + 16384);                  // NN+1 (pad 100004)
  int* col    = rowptr + 100004;                      // NE
  int* gcursor= col + NE;                             // NB (pad 784)
  int* bcnt   = gcursor + 784;                        // NB (pad 784)
  int* bbase  = bcnt + 784;                           // NB+1 (pad 784)
  int* bh     = bbase + 784;                          // NWG*NB (pad 305764)
  uint2* binned = (uint2*)(bh + 305764);              // NE x 8B

  float* out = (float*)d_out;

  // ---- CSR build (no global per-node atomics) ----
  k_bhist<<<NWG, 256, 0, stream>>>(dst, bh, NE);
  k_breduce<<<NB, 64, 0, stream>>>(bh, bcnt);
  k_bscan<<<1, 256, 0, stream>>>(bcnt, bbase, gcursor);
  k_binA<<<NWG, 256, 0, stream>>>(src, dst, gcursor, binned, NE);
  k_binB<<<NB, 256, 0, stream>>>(binned, bbase, rowptr, col, dinv);

  // ---- weight prep ----
  k_wconv<<<64, 256, 0, stream>>>(W1, wt1);
  k_uvec<<<1, 256, 0, stream>>>(W2, Wlin, b2, uv);

  const int gemm_grid = (NN + 63) / 64;
  const int gth_grid = (NN + 3) / 4;

  // conv1: hs = bf16(dinv*(x@W1)); q = score-projection of relu(gather)
  k_gemm_mfma<<<gemm_grid, 256, 0, stream>>>(x, wt1, dinv, (unsigned short*)hs, NN);
  k_gather1q<<<gth_grid, 256, 0, stream>>>((const uint4*)hs, dinv, rowptr, col, b1, uv,
                                           (float2*)qbuf, NN);

  // conv2 + score head collapsed: sv = dinv*(q_self + sum_nbr q) + c
  k_qagg<<<(NN + 255) / 256, 256, 0, stream>>>((const float2*)qbuf, dinv, rowptr, col, uv,
                                               (float2*)sv, NN);

  // pair outputs
  k_pairs<<<(NP + 255) / 256, 256, 0, stream>>>((const float2*)sv, Iidx, Jidx, blin, out, NP);
}

// Round 10
// 289.332 us; speedup vs baseline: 5.8255x; 1.0406x over previous
//
#include <hip/hip_runtime.h>
#include <hip/hip_bf16.h>
#include <math.h>

#define NN 100000
#define NE 1600000
#define NP 500000
#define HD 128
#define NPB 128                    // nodes per bucket (pow2)
#define NB 782                     // ceil(NN/NPB)
#define CAP 2560                   // bucket capacity (mean 2048, +11 sigma)
#define CHUNK 4096                 // edges per binning workgroup
#define NWG 391                    // ceil(NE/CHUNK)

typedef __attribute__((ext_vector_type(8))) short short8;   // 8 bf16 = 4 VGPRs
typedef __attribute__((ext_vector_type(4))) float f32x4;

// ---- bf16 helpers ----
__device__ __forceinline__ float bf_lo(unsigned int u) { return __uint_as_float(u << 16); }
__device__ __forceinline__ float bf_hi(unsigned int u) { return __uint_as_float(u & 0xffff0000u); }
__device__ __forceinline__ unsigned short bf16_rne(float f) {
  unsigned int u = __float_as_uint(f);
  u = (u + 0x7fffu + ((u >> 16) & 1u)) >> 16;
  return (unsigned short)u;
}
__device__ __forceinline__ void acc_row(float* ax, uint4 u) {
  ax[0] += bf_lo(u.x); ax[1] += bf_hi(u.x);
  ax[2] += bf_lo(u.y); ax[3] += bf_hi(u.y);
  ax[4] += bf_lo(u.z); ax[5] += bf_hi(u.z);
  ax[6] += bf_lo(u.w); ax[7] += bf_hi(u.w);
}

// ---------------- cursor init: gcursor[b] = b*CAP ----------------
__global__ void k_initgcur(int* __restrict__ gcursor) {
  int b = blockIdx.x * 256 + threadIdx.x;
  if (b < NB) gcursor[b] = b * CAP;
}

// ---- binA: bin edges into fixed-capacity bucket regions (8B entries) ----
__global__ __launch_bounds__(256) void k_binA(const int* __restrict__ src,
                                              const int* __restrict__ dst,
                                              int* __restrict__ gcursor,
                                              uint2* __restrict__ binned, int ne) {
  __shared__ int hist[NB];
  __shared__ int base[NB];
  const int t = threadIdx.x;
  const int e0 = blockIdx.x * CHUNK;

  for (int i = t; i < NB; i += 256) hist[i] = 0;
  __syncthreads();

#pragma unroll
  for (int k = 0; k < CHUNK / 256; ++k) {
    int e = e0 + k * 256 + t;
    if (e < ne) atomicAdd(&hist[dst[e] >> 7], 1);
  }
  __syncthreads();

  for (int i = t; i < NB; i += 256) {
    int c = hist[i];
    base[i] = c ? atomicAdd(&gcursor[i], c) : 0;
    hist[i] = 0;
  }
  __syncthreads();

#pragma unroll
  for (int k = 0; k < CHUNK / 256; ++k) {
    int e = e0 + k * 256 + t;
    if (e < ne) {
      int d = dst[e];
      int b = d >> 7;
      int pos = base[b] + atomicAdd(&hist[b], 1);
      binned[pos] = make_uint2((unsigned int)src[e], (unsigned int)d);
    }
  }
}

// ---- binB: per-node count (LDS) -> rows(start,end) + dinv, then CSR placement ----
__global__ __launch_bounds__(256) void k_binB(const uint2* __restrict__ binned,
                                              const int* __restrict__ gcursor,
                                              int2* __restrict__ rows,
                                              int* __restrict__ col,
                                              float* __restrict__ dinv) {
  __shared__ int hcnt[NPB];
  __shared__ int sc[NPB];
  __shared__ int lcur[NPB];
  const int b = blockIdx.x;
  const int t = threadIdx.x;
  const int node0 = b * NPB;
  const int node1 = (node0 + NPB > NN) ? NN : node0 + NPB;
  const int nnode = node1 - node0;
  if (t < NPB) hcnt[t] = 0;
  __syncthreads();

  const int gbase = b * CAP;
  const int gend = gcursor[b];   // after binA: b*CAP + bucket count
  for (int i = gbase + t; i < gend; i += 256)
    atomicAdd(&hcnt[binned[i].y - node0], 1);
  __syncthreads();

  int v = (t < NPB) ? hcnt[t] : 0;
  if (t < NPB) sc[t] = v;
  __syncthreads();
#pragma unroll
  for (int o = 1; o < NPB; o <<= 1) {
    int add = (t < NPB && t >= o) ? sc[t - o] : 0;
    __syncthreads();
    if (t < NPB) sc[t] += add;
    __syncthreads();
  }
  if (t < nnode) {
    int rp = gbase + sc[t] - v;   // exclusive prefix within bucket
    rows[node0 + t] = make_int2(rp, rp + v);
    lcur[t] = rp;
    dinv[node0 + t] = rsqrtf((float)v + 1.0f);
  }
  __syncthreads();

  for (int i = gbase + t; i < gend; i += 256) {
    uint2 p = binned[i];
    int pos = atomicAdd(&lcur[p.y - node0], 1);
    col[pos] = (int)p.x;
  }
}

// ---------------- W transpose+cast: Wt[n][k] = bf16(W[k][n]) ----------------
__global__ void k_wconv(const float* __restrict__ W, unsigned short* __restrict__ Wt) {
  int t = blockIdx.x * 256 + threadIdx.x;  // 16384
  int n = t >> 7, k = t & 127;
  Wt[t] = bf16_rne(W[k * HD + n]);
}

// ---------------- u-vector prep: u1 = W2@Wl[:128], u2 = W2@Wl[128:], c1/c2 = b2.Wl ----------------
// uv layout: [0..127]=u1, [128..255]=u2, [256]=c1, [257]=c2
__global__ __launch_bounds__(256) void k_uvec(const float* __restrict__ W2,
                                              const float* __restrict__ Wl,
                                              const float* __restrict__ b2,
                                              float* __restrict__ uv) {
  __shared__ float sh[256];
  const int t = threadIdx.x;
  const int half = t >> 7;
  const int k = t & 127;
  const float* wl = Wl + half * 128;
  float s = 0.f;
  for (int c = 0; c < 128; ++c) s += W2[k * HD + c] * wl[c];
  uv[half * 128 + k] = s;

  sh[t] = b2[k] * Wl[half * 128 + k];
  __syncthreads();
  for (int o = 64; o > 0; o >>= 1) {
    if ((t & 127) < o) sh[t] += sh[t + o];
    __syncthreads();
  }
  if (t == 0) uv[256] = sh[0];
  if (t == 128) uv[257] = sh[128];
}

// ---------------- MFMA GEMM: hs[n][c] = bf16( dinv[n] * (X @ W)[n][c] ) ----------------
__global__ __launch_bounds__(256) void k_gemm_mfma(const float* __restrict__ X,
                                                   const unsigned short* __restrict__ Wt,
                                                   const float* __restrict__ dinv,
                                                   unsigned short* __restrict__ hs,
                                                   int nrows) {
  const int wave = threadIdx.x >> 6;
  const int lane = threadIdx.x & 63;
  const int row0 = blockIdx.x * 64 + wave * 16;
  if (row0 >= nrows) return;
  const int lm = lane & 15;   // A-row / C-col
  const int lq = lane >> 4;   // quad

  int arow = row0 + lm;
  int arowc = arow < nrows ? arow : nrows - 1;  // clamp (stores are guarded)

  short8 afrag[4];
#pragma unroll
  for (int kc = 0; kc < 4; ++kc) {
    int k0 = kc * 32 + lq * 8;
    const float4* p = (const float4*)(X + (size_t)arowc * HD + k0);
    float4 f0 = p[0], f1 = p[1];
    short8 a;
    a[0] = (short)bf16_rne(f0.x); a[1] = (short)bf16_rne(f0.y);
    a[2] = (short)bf16_rne(f0.z); a[3] = (short)bf16_rne(f0.w);
    a[4] = (short)bf16_rne(f1.x); a[5] = (short)bf16_rne(f1.y);
    a[6] = (short)bf16_rne(f1.z); a[7] = (short)bf16_rne(f1.w);
    afrag[kc] = a;
  }

  float dv[4];
#pragma unroll
  for (int r = 0; r < 4; ++r) {
    int row = row0 + lq * 4 + r;
    dv[r] = dinv[row < nrows ? row : 0];
  }

#pragma unroll
  for (int nt = 0; nt < 8; ++nt) {
    f32x4 acc = {0.f, 0.f, 0.f, 0.f};
    const unsigned short* Wb = Wt + (size_t)(nt * 16 + lm) * HD + lq * 8;
#pragma unroll
    for (int kc = 0; kc < 4; ++kc) {
      short8 bfrag = *(const short8*)(Wb + kc * 32);
      acc = __builtin_amdgcn_mfma_f32_16x16x32_bf16(afrag[kc], bfrag, acc, 0, 0, 0);
    }
#pragma unroll
    for (int r = 0; r < 4; ++r) {
      int row = row0 + lq * 4 + r;
      if (row < nrows)
        hs[(size_t)row * HD + nt * 16 + lm] = bf16_rne(acc[r] * dv[r]);
    }
  }
}

// ---------------- gather1 + relu + fused score-projection ----------------
// One wave per node. lane = sub*16 + fl; sub = edge slot, fl = 16B feature slice.
// x2 unroll (8 edges in flight) — x4 thrashed per-XCD L2 (R9: FETCH 190->269MB).
__global__ __launch_bounds__(256) void k_gather1q(const uint4* __restrict__ hs4,
                                                  const float* __restrict__ dinv,
                                                  const int2* __restrict__ rows,
                                                  const int* __restrict__ col,
                                                  const float* __restrict__ bias,
                                                  const float* __restrict__ uv,
                                                  float2* __restrict__ q, int n) {
  int node = blockIdx.x * 4 + (threadIdx.x >> 6);
  int lane = threadIdx.x & 63;
  if (node >= n) return;
  const int sub = lane >> 4;
  const int fl = lane & 15;
  int2 be = rows[node];
  int beg = be.x, end = be.y;

  float ax[8] = {0.f, 0.f, 0.f, 0.f, 0.f, 0.f, 0.f, 0.f};
  if (sub == 0) acc_row(ax, hs4[(size_t)node * 16 + fl]);  // self term

  int e = beg + sub;
  for (; e + 4 < end; e += 8) {
    int s0 = col[e];
    int s1 = col[e + 4];
    uint4 u0 = hs4[(size_t)s0 * 16 + fl];
    uint4 u1 = hs4[(size_t)s1 * 16 + fl];
    acc_row(ax, u0);
    acc_row(ax, u1);
  }
  if (e < end) acc_row(ax, hs4[(size_t)col[e] * 16 + fl]);

  // combine the 4 edge slots (all lanes end with full sums, replicated)
#pragma unroll
  for (int i = 0; i < 8; ++i) {
    ax[i] += __shfl_xor(ax[i], 16);
    ax[i] += __shfl_xor(ax[i], 32);
  }

  float di = dinv[node];
  float4 b0 = ((const float4*)bias)[fl * 2];
  float4 b1 = ((const float4*)bias)[fl * 2 + 1];
  float h[8];
  h[0] = fmaxf(ax[0] * di + b0.x, 0.f); h[1] = fmaxf(ax[1] * di + b0.y, 0.f);
  h[2] = fmaxf(ax[2] * di + b0.z, 0.f); h[3] = fmaxf(ax[3] * di + b0.w, 0.f);
  h[4] = fmaxf(ax[4] * di + b1.x, 0.f); h[5] = fmaxf(ax[5] * di + b1.y, 0.f);
  h[6] = fmaxf(ax[6] * di + b1.z, 0.f); h[7] = fmaxf(ax[7] * di + b1.w, 0.f);

  float4 ua0 = ((const float4*)uv)[fl * 2];
  float4 ua1 = ((const float4*)uv)[fl * 2 + 1];
  float4 ub0 = ((const float4*)uv)[32 + fl * 2];
  float4 ub1 = ((const float4*)uv)[32 + fl * 2 + 1];
  float p1 = h[0] * ua0.x + h[1] * ua0.y + h[2] * ua0.z + h[3] * ua0.w +
             h[4] * ua1.x + h[5] * ua1.y + h[6] * ua1.z + h[7] * ua1.w;
  float p2 = h[0] * ub0.x + h[1] * ub0.y + h[2] * ub0.z + h[3] * ub0.w +
             h[4] * ub1.x + h[5] * ub1.y + h[6] * ub1.z + h[7] * ub1.w;
#pragma unroll
  for (int o = 8; o > 0; o >>= 1) {
    p1 += __shfl_down(p1, o);
    p2 += __shfl_down(p2, o);
  }
  if (lane == 0) q[node] = make_float2(p1 * di, p2 * di);
}

// ---------------- q aggregation: sv = dinv*(q_self + sum_nbr q) + c ----------------
__global__ __launch_bounds__(256) void k_qagg(const float2* __restrict__ q,
                                              const float* __restrict__ dinv,
                                              const int2* __restrict__ rows,
                                              const int* __restrict__ col,
                                              const float* __restrict__ uv,
                                              float2* __restrict__ sv, int n) {
  int i = blockIdx.x * 256 + threadIdx.x;
  if (i >= n) return;
  int2 be = rows[i];
  int beg = be.x, end = be.y;
  float2 a = q[i];
  float a1 = a.x, a2 = a.y;
  int e = beg;
  for (; e + 3 < end; e += 4) {
    float2 q0 = q[col[e]];
    float2 q1 = q[col[e + 1]];
    float2 q2 = q[col[e + 2]];
    float2 q3 = q[col[e + 3]];
    a1 += (q0.x + q1.x) + (q2.x + q3.x);
    a2 += (q0.y + q1.y) + (q2.y + q3.y);
  }
  for (; e < end; ++e) {
    float2 qq = q[col[e]];
    a1 += qq.x; a2 += qq.y;
  }
  float di = dinv[i];
  sv[i] = make_float2(a1 * di + uv[256], a2 * di + uv[257]);
}

// ---------------- pair outputs ----------------
__global__ void k_pairs(const float2* __restrict__ s, const int* __restrict__ I,
                        const int* __restrict__ J, const float* __restrict__ blin,
                        float* __restrict__ out, int np) {
  int p = blockIdx.x * 256 + threadIdx.x;
  if (p < np) {
    float v = s[I[p]].x + s[J[p]].y + blin[0];
    out[p] = 1.f / (1.f + __expf(-v));
  }
}

extern "C" void kernel_launch(void* const* d_in, const int* in_sizes, int n_in,
                              void* d_out, int out_size, void* d_ws, size_t ws_size,
                              hipStream_t stream) {
  const float* x     = (const float*)d_in[0];
  const int*   eidx  = (const int*)d_in[1];
  const int*   Iidx  = (const int*)d_in[2];
  const int*   Jidx  = (const int*)d_in[3];
  const float* W1    = (const float*)d_in[4];
  const float* b1    = (const float*)d_in[5];
  const float* W2    = (const float*)d_in[6];
  const float* b2    = (const float*)d_in[7];
  const float* Wlin  = (const float*)d_in[8];
  const float* blin  = (const float*)d_in[9];
  const int* src = eidx;
  const int* dst = eidx + NE;

  // workspace layout (int offsets; 8B-aligned where needed)
  float* ws   = (float*)d_ws;
  float* dinv = ws;                                   // 100000
  float* sv   = dinv + 100000;                        // 200000 (float2 per node)
  float* qbuf = sv + 200000;                          // 200000 (float2 per node)
  float* uv   = qbuf + 200000;                        // 260 -> pad 264
  unsigned int* hs  = (unsigned int*)(uv + 264);      // NN*64 (bf16x2)
  unsigned short* wt1 = (unsigned short*)(hs + (size_t)NN * 64);  // 16384 bf16
  int2* rows  = (int2*)(wt1 + 16384);                 // NN int2 (200000 ints, 8B-aligned)
  int* col    = (int*)(rows + NN);                    // NB*CAP = 2001920
  int* gcursor= col + NB * CAP;                       // NB (pad 784)
  uint2* binned = (uint2*)(gcursor + 784);            // NB*CAP x 8B

  float* out = (float*)d_out;

  // ---- CSR build (fixed-capacity buckets; no global pre-scan) ----
  k_initgcur<<<(NB + 255) / 256, 256, 0, stream>>>(gcursor);
  k_binA<<<NWG, 256, 0, stream>>>(src, dst, gcursor, binned, NE);
  k_binB<<<NB, 256, 0, stream>>>(binned, gcursor, rows, col, dinv);

  // ---- weight prep ----
  k_wconv<<<64, 256, 0, stream>>>(W1, wt1);
  k_uvec<<<1, 256, 0, stream>>>(W2, Wlin, b2, uv);

  const int gemm_grid = (NN + 63) / 64;
  const int gth_grid = (NN + 3) / 4;

  // conv1: hs = bf16(dinv*(x@W1)); q = score-projection of relu(gather)
  k_gemm_mfma<<<gemm_grid, 256, 0, stream>>>(x, wt1, dinv, (unsigned short*)hs, NN);
  k_gather1q<<<gth_grid, 256, 0, stream>>>((const uint4*)hs, dinv, rows, col, b1, uv,
                                           (float2*)qbuf, NN);

  // conv2 + score head collapsed: sv = dinv*(q_self + sum_nbr q) + c
  k_qagg<<<(NN + 255) / 256, 256, 0, stream>>>((const float2*)qbuf, dinv, rows, col, uv,
                                               (float2*)sv, NN);

  // pair outputs
  k_pairs<<<(NP + 255) / 256, 256, 0, stream>>>((const float2*)sv, Iidx, Jidx, blin, out, NP);
}